// Round 8
// baseline (144.023 us; speedup 1.0000x reference)
//
#include <hip/hip_runtime.h>
#include <hip/hip_bf16.h>

#define HH 56
#define WW 56
#define NPOS 3136
#define BATCH 2
#define HEADS 8

typedef __attribute__((ext_vector_type(4))) float floatx4;
typedef __attribute__((ext_vector_type(8))) short short8;

static __device__ __forceinline__ ushort f2b(float f) {
    __hip_bfloat16 h = __float2bfloat16(f);
    return *reinterpret_cast<ushort*>(&h);
}
static __device__ __forceinline__ float b2f(ushort u) {
    return __uint_as_float(((uint)u) << 16);
}

// fl32(10^(-j/4)) == np.float32 inv-freq table
__constant__ float INVF[16] = {
    1.0f,   0.5623413251903491f,   0.31622776601683794f,   0.17782794100389228f,
    0.1f,   0.05623413251903491f,  0.031622776601683794f,  0.017782794100389228f,
    0.01f,  0.005623413251903491f, 0.0031622776601683794f, 0.0017782794100389228f,
    0.001f, 0.0005623413251903491f,0.00031622776601683794f,0.00017782794100389228f
};

// ---------------------------------------------------------------------------
// Kernel 1: QKV GEMM (M=6272, K=256, N=768). fp32 in -> bf16 LDS -> MFMA.
// RoPE in epilogue. q -> d_out FP32 [m][head*32+d]; k,v -> ws bf16.
// C/D layout (HW-probe verified r5): col = lane&15, row = (lane>>4)*4 + reg.
// ---------------------------------------------------------------------------
__global__ __launch_bounds__(256) void qkv_gemm(
    const float* __restrict__ x, const float* __restrict__ w,
    float* __restrict__ qa, ushort* __restrict__ kws, ushort* __restrict__ vws)
{
    __shared__ ushort Asm[64 * 40];   // [m][k]
    __shared__ ushort Bsm[64 * 40];   // [n][k]
    const int t = threadIdx.x;
    const int m0 = blockIdx.y * 64;
    const int n0 = blockIdx.x * 64;
    const int lane = t & 63, wv = t >> 6;
    const int qm = lane & 15, quad = lane >> 4;

    floatx4 acc[4];
#pragma unroll
    for (int i = 0; i < 4; ++i) acc[i] = (floatx4){0.f, 0.f, 0.f, 0.f};

    for (int k0 = 0; k0 < 256; k0 += 32) {
#pragma unroll
        for (int i = 0; i < 2; ++i) {
            int p = t + 256 * i;
            int row = p >> 3, f4 = p & 7;
            float4 v = *(const float4*)&x[(size_t)(m0 + row) * 256 + k0 + f4 * 4];
            ushort4 h;
            h.x = f2b(v.x); h.y = f2b(v.y); h.z = f2b(v.z); h.w = f2b(v.w);
            *(ushort4*)&Asm[row * 40 + f4 * 4] = h;
        }
#pragma unroll
        for (int i = 0; i < 8; ++i) {
            int e = t + 256 * i;
            int kk = e >> 6, nn = e & 63;
            Bsm[nn * 40 + kk] = f2b(w[(size_t)(k0 + kk) * 768 + n0 + nn]);
        }
        __syncthreads();
        short8 af = *(const short8*)&Asm[(wv * 16 + qm) * 40 + quad * 8];
#pragma unroll
        for (int nt = 0; nt < 4; ++nt) {
            short8 bf = *(const short8*)&Bsm[(nt * 16 + qm) * 40 + quad * 8];
            acc[nt] = __builtin_amdgcn_mfma_f32_16x16x32_bf16(af, bf, acc[nt], 0, 0, 0);
        }
        __syncthreads();
    }

    const int whichB = n0 >> 8;          // block-uniform: 0=q 1=k 2=v
    const int h0 = (n0 >> 5) & 7;
#pragma unroll
    for (int r = 0; r < 4; ++r) {
        int m = m0 + wv * 16 + quad * 4 + r;
        int b = (m >= NPOS) ? 1 : 0;
        int pos = m - b * NPOS;
        float cf[2], sf[2];
        if (whichB < 2) {
            float posf = (float)pos;
            __sincosf(posf * INVF[qm >> 1], &sf[0], &cf[0]);
            __sincosf(posf * INVF[8 + (qm >> 1)], &sf[1], &cf[1]);
        }
#pragma unroll
        for (int nt = 0; nt < 4; ++nt) {
            int par = nt & 1;
            int d = par * 16 + qm;
            int head = h0 + (nt >> 1);
            float val = acc[nt][r];
            if (whichB < 2) {
                float other = __shfl_xor(val, 1);   // d parity == lane parity
                val = (lane & 1) ? (val * cf[par] + other * sf[par])
                                 : (val * cf[par] - other * sf[par]);
            }
            if (whichB == 0) {
                qa[(size_t)m * 256 + head * 32 + d] = val;           // FP32
            } else {
                ushort* dst = (whichB == 1) ? kws : vws;
                dst[(size_t)(((b << 3) + head) * NPOS + pos) * 32 + d] = f2b(val);
            }
        }
    }
}

// ---------------------------------------------------------------------------
// Kernel 2: neighborhood attention (window=7). q fp32 from d_out, k/v bf16
// from ws (LDS-staged), output fp32 overwrites q slice in d_out.
// ---------------------------------------------------------------------------
__global__ __launch_bounds__(256) void nattn(
    const ushort* __restrict__ kws, const ushort* __restrict__ vws, float* qa)
{
    __shared__ ushort Ksm[196 * 32];
    __shared__ ushort Vsm[196 * 32];
    const int t = threadIdx.x;
    const int bh = blockIdx.y;
    const int b = bh >> 3, head = bh & 7;
    const int ti = blockIdx.x / 7, tj = blockIdx.x % 7;
    const int ty0 = ti * 8, tx0 = tj * 8;
    const int r0 = min(max(ty0 - 3, 0), HH - 14);
    const int c0 = min(max(tx0 - 3, 0), WW - 14);
    const ushort* kbase = kws + (size_t)bh * NPOS * 32;
    const ushort* vbase = vws + (size_t)bh * NPOS * 32;

    for (int idx = t; idx < 196 * 4; idx += 256) {
        int p = idx >> 2, ch = idx & 3;
        int g = ((r0 + p / 14) * WW + (c0 + p % 14)) * 32 + ch * 8;
        *(uint4*)&Ksm[p * 32 + ch * 8] = *(const uint4*)&kbase[g];
        *(uint4*)&Vsm[p * 32 + ch * 8] = *(const uint4*)&vbase[g];
    }
    __syncthreads();

    const int lane = t & 63, wv = t >> 6;
    const int qsub = lane & 15, part = lane >> 4;
    const int qi = wv * 16 + qsub;
    const int qy = ty0 + (qi >> 3), qx = tx0 + (qi & 7);
    const int pos = qy * WW + qx;
    float* qptr = qa + (size_t)(b * NPOS + pos) * 256 + head * 32;

    float qf[32];
#pragma unroll
    for (int c4 = 0; c4 < 8; ++c4) {
        float4 v = *(const float4*)&qptr[c4 * 4];
        qf[4 * c4] = v.x; qf[4 * c4 + 1] = v.y; qf[4 * c4 + 2] = v.z; qf[4 * c4 + 3] = v.w;
    }

    const int rs = min(max(qy - 3, 0), HH - 7) - r0;
    const int cs = min(max(qx - 3, 0), WW - 7) - c0;

    float sarr[13];
    float mx = -1e30f;
#pragma unroll
    for (int j = 0; j < 13; ++j) {
        int kk = part + 4 * j;
        sarr[j] = -1e30f;
        if (kk < 49) {
            int off = ((rs + kk / 7) * 14 + (cs + kk % 7)) * 16;
            const uint* Kp = (const uint*)Ksm + off;
            float s = 0.f;
#pragma unroll
            for (int c2 = 0; c2 < 16; ++c2) {
                uint u = Kp[c2];
                s += qf[2 * c2] * b2f((ushort)u) + qf[2 * c2 + 1] * b2f((ushort)(u >> 16));
            }
            s *= 0.17677669529663687f;  // 32^-0.5
            sarr[j] = s;
            mx = fmaxf(mx, s);
        }
    }
    mx = fmaxf(mx, __shfl_xor(mx, 16));
    mx = fmaxf(mx, __shfl_xor(mx, 32));

    float sum = 0.f;
    float facc[32];
#pragma unroll
    for (int c = 0; c < 32; ++c) facc[c] = 0.f;
#pragma unroll
    for (int j = 0; j < 13; ++j) {
        int kk = part + 4 * j;
        if (kk < 49) {
            float e = __expf(sarr[j] - mx);
            sum += e;
            int off = ((rs + kk / 7) * 14 + (cs + kk % 7)) * 16;
            const uint* Vp = (const uint*)Vsm + off;
#pragma unroll
            for (int c2 = 0; c2 < 16; ++c2) {
                uint u = Vp[c2];
                facc[2 * c2]     += e * b2f((ushort)u);
                facc[2 * c2 + 1] += e * b2f((ushort)(u >> 16));
            }
        }
    }
    sum += __shfl_xor(sum, 16);
    sum += __shfl_xor(sum, 32);
#pragma unroll
    for (int c = 0; c < 32; ++c) {
        facc[c] += __shfl_xor(facc[c], 16);
        facc[c] += __shfl_xor(facc[c], 32);
    }

    if (part == 0) {
        float inv = 1.f / sum;
#pragma unroll
        for (int c4 = 0; c4 < 8; ++c4) {
            float4 o;
            o.x = facc[4 * c4]     * inv;
            o.y = facc[4 * c4 + 1] * inv;
            o.z = facc[4 * c4 + 2] * inv;
            o.w = facc[4 * c4 + 3] * inv;
            *(float4*)&qptr[c4 * 4] = o;                             // FP32
        }
    }
}

// ---------------------------------------------------------------------------
// Kernel 3: in-place projection GEMM on d_out (M=6272, K=256, N=256) + bias.
// Stages its own 64 fp32 A-rows (->bf16 LDS) before overwriting them. FP32 out.
// ---------------------------------------------------------------------------
__global__ __launch_bounds__(256) void proj_gemm(
    const float* __restrict__ w, const float* __restrict__ bias, float* out)
{
    __shared__ ushort Apad[64 * 264];
    __shared__ ushort Bsm[256 * 40];
    const int t = threadIdx.x;
    const int m0 = blockIdx.x * 64;
    const int lane = t & 63, wv = t >> 6;
    const int qm = lane & 15, quad = lane >> 4;

    {   // stage 64 x 256 fp32 rows -> bf16 LDS
        int row = t >> 2, cb = (t & 3) * 64;
        const float4* src = (const float4*)&out[(size_t)(m0 + row) * 256 + cb];
#pragma unroll
        for (int i = 0; i < 16; ++i) {
            float4 v = src[i];
            ushort4 h;
            h.x = f2b(v.x); h.y = f2b(v.y); h.z = f2b(v.z); h.w = f2b(v.w);
            *(ushort4*)&Apad[row * 264 + cb + i * 4] = h;
        }
    }

    floatx4 acc[4][4];
#pragma unroll
    for (int i = 0; i < 4; ++i)
#pragma unroll
        for (int j = 0; j < 4; ++j) acc[i][j] = (floatx4){0.f, 0.f, 0.f, 0.f};

    __syncthreads();

    for (int k0 = 0; k0 < 256; k0 += 32) {
#pragma unroll
        for (int i = 0; i < 32; ++i) {
            int e = t + 256 * i;
            int kk = e >> 8, nn = e & 255;
            Bsm[nn * 40 + kk] = f2b(w[(size_t)(k0 + kk) * 256 + nn]);
        }
        __syncthreads();
        short8 af[4];
#pragma unroll
        for (int mt = 0; mt < 4; ++mt)
            af[mt] = *(const short8*)&Apad[(mt * 16 + qm) * 264 + k0 + quad * 8];
#pragma unroll
        for (int nt = 0; nt < 4; ++nt) {
            short8 bf = *(const short8*)&Bsm[(wv * 64 + nt * 16 + qm) * 40 + quad * 8];
#pragma unroll
            for (int mt = 0; mt < 4; ++mt)
                acc[mt][nt] = __builtin_amdgcn_mfma_f32_16x16x32_bf16(af[mt], bf, acc[mt][nt], 0, 0, 0);
        }
        __syncthreads();
    }

#pragma unroll
    for (int nt = 0; nt < 4; ++nt) {
        int c = wv * 64 + nt * 16 + qm;
        float bv = bias[c];
#pragma unroll
        for (int mt = 0; mt < 4; ++mt) {
#pragma unroll
            for (int r = 0; r < 4; ++r) {
                int m = m0 + mt * 16 + quad * 4 + r;
                out[(size_t)m * 256 + c] = acc[mt][nt][r] + bv;      // FP32
            }
        }
    }
}

// ---------------------------------------------------------------------------
extern "C" void kernel_launch(void* const* d_in, const int* in_sizes, int n_in,
                              void* d_out, int out_size, void* d_ws, size_t ws_size,
                              hipStream_t stream)
{
    const float* x     = (const float*)d_in[0];
    const float* wqkv  = (const float*)d_in[1];   // (256,768) row-major, as reference
    const float* wproj = (const float*)d_in[2];   // (256,256) row-major
    const float* bproj = (const float*)d_in[3];
    float* out = (float*)d_out;                   // FP32 output (reference dtype)

    // ws (>=6.43MB verified r7): k,v bf16 [16][3136][32]
    char* ws = (char*)d_ws;
    ushort* kws = (ushort*)ws;
    ushort* vws = (ushort*)(ws + (size_t)BATCH * HEADS * NPOS * 32 * 2);

    hipLaunchKernelGGL(qkv_gemm, dim3(12, 98), dim3(256), 0, stream,
                       x, wqkv, out, kws, vws);
    hipLaunchKernelGGL(nattn, dim3(49, BATCH * HEADS), dim3(256), 0, stream,
                       kws, vws, out);
    hipLaunchKernelGGL(proj_gemm, dim3(98), dim3(256), 0, stream,
                       wproj, bproj, out);
}

// Round 9
// 138.475 us; speedup vs baseline: 1.0401x; 1.0401x over previous
//
#include <hip/hip_runtime.h>
#include <hip/hip_bf16.h>

#define HH 56
#define WW 56
#define NPOS 3136
#define BATCH 2
#define HEADS 8

typedef __attribute__((ext_vector_type(4))) float floatx4;
typedef __attribute__((ext_vector_type(8))) short short8;

static __device__ __forceinline__ ushort f2b(float f) {
    __hip_bfloat16 h = __float2bfloat16(f);
    return *reinterpret_cast<ushort*>(&h);
}
static __device__ __forceinline__ float b2f(ushort u) {
    return __uint_as_float(((uint)u) << 16);
}

// async global->LDS, 16B per lane. LDS dest = wave-uniform base + lane*16.
static __device__ __forceinline__ void async16(const ushort* g, ushort* l) {
    __builtin_amdgcn_global_load_lds(
        (const __attribute__((address_space(1))) unsigned int*)g,
        (__attribute__((address_space(3))) unsigned int*)l, 16, 0, 0);
}

// fl32(10^(-j/4)) == np.float32 inv-freq table
__constant__ float INVF[16] = {
    1.0f,   0.5623413251903491f,   0.31622776601683794f,   0.17782794100389228f,
    0.1f,   0.05623413251903491f,  0.031622776601683794f,  0.017782794100389228f,
    0.01f,  0.005623413251903491f, 0.0031622776601683794f, 0.0017782794100389228f,
    0.001f, 0.0005623413251903491f,0.00031622776601683794f,0.00017782794100389228f
};

// ===========================================================================
// FAST PATH
// ===========================================================================

// Prepass: xb (bf16), wqkvT [n][k] bf16, wprojT [n][k] bf16, rope table.
// grid = 1568 (xb) + 196 (rope) + 48 (wqkvT) + 16 (wprojT) = 1828
__global__ __launch_bounds__(256) void prepass(
    const float* __restrict__ x, const float* __restrict__ wqkv,
    const float* __restrict__ wproj,
    ushort* __restrict__ xb, ushort* __restrict__ wqkvT,
    ushort* __restrict__ wprojT, float* __restrict__ ropeT)
{
    __shared__ ushort Ls[64 * 65];
    const int bid = blockIdx.x, t = threadIdx.x;
    if (bid < 1568) {                       // x fp32 -> bf16, 4 elems/thread
        int i = (bid * 256 + t) * 4;
        float4 v = *(const float4*)&x[i];
        ushort4 h; h.x = f2b(v.x); h.y = f2b(v.y); h.z = f2b(v.z); h.w = f2b(v.w);
        *(ushort4*)&xb[i] = h;
    } else if (bid < 1764) {                // rope table [pos][16] (cos,sin)
        int i = (bid - 1568) * 256 + t;
        int pos = i >> 4, pr = i & 15;
        float s, c;
        __sincosf((float)pos * INVF[pr], &s, &c);
        ropeT[2 * i] = c; ropeT[2 * i + 1] = s;
    } else if (bid < 1812) {                // wqkv (256,768) -> wqkvT (768,256)
        int l = bid - 1764;
        int nb = (l % 12) * 64, kb = (l / 12) * 64;
#pragma unroll
        for (int i = 0; i < 16; ++i) {
            int e = t + 256 * i, kk = e >> 6, nn = e & 63;
            Ls[kk * 65 + nn] = f2b(wqkv[(size_t)(kb + kk) * 768 + nb + nn]);
        }
        __syncthreads();
#pragma unroll
        for (int i = 0; i < 16; ++i) {
            int e = t + 256 * i, nn = e >> 6, kk = e & 63;
            wqkvT[(size_t)(nb + nn) * 256 + kb + kk] = Ls[kk * 65 + nn];
        }
    } else {                                // wproj (256,256) -> wprojT
        int l = bid - 1812;
        int nb = (l & 3) * 64, kb = (l >> 2) * 64;
#pragma unroll
        for (int i = 0; i < 16; ++i) {
            int e = t + 256 * i, kk = e >> 6, nn = e & 63;
            Ls[kk * 65 + nn] = f2b(wproj[(size_t)(kb + kk) * 256 + nb + nn]);
        }
        __syncthreads();
#pragma unroll
        for (int i = 0; i < 16; ++i) {
            int e = t + 256 * i, nn = e >> 6, kk = e & 63;
            wprojT[(size_t)(nb + nn) * 256 + kb + kk] = Ls[kk * 65 + nn];
        }
    }
}

// QKV GEMM 128x128 tile, global_load_lds staging, RoPE-table epilogue.
// grid (6, 49)
__global__ __launch_bounds__(256) void qkv_fast(
    const ushort* __restrict__ xb, const ushort* __restrict__ wqkvT,
    const float* __restrict__ ropeT,
    float* __restrict__ qa, ushort* __restrict__ kws, ushort* __restrict__ vws)
{
    __shared__ ushort Ab[128 * 32];
    __shared__ ushort Bb[128 * 32];
    const int t = threadIdx.x;
    const int lane = t & 63, wv = t >> 6;
    const int qm = lane & 15, quad = lane >> 4;
    const int m0 = blockIdx.y * 128, n0 = blockIdx.x * 128;
    const int wr = wv >> 1, wc = wv & 1;
    const int srow = lane >> 2, scol = (lane & 3) * 8;

    floatx4 acc[4][4];
#pragma unroll
    for (int i = 0; i < 4; ++i)
#pragma unroll
        for (int j = 0; j < 4; ++j) acc[i][j] = (floatx4){0.f, 0.f, 0.f, 0.f};

    for (int k0 = 0; k0 < 256; k0 += 32) {
#pragma unroll
        for (int j = 0; j < 2; ++j) {
            int rbase = wv * 32 + j * 16;
            async16(&xb[(size_t)(m0 + rbase + srow) * 256 + k0 + scol], &Ab[rbase * 32]);
            async16(&wqkvT[(size_t)(n0 + rbase + srow) * 256 + k0 + scol], &Bb[rbase * 32]);
        }
        __syncthreads();
        short8 af[4], bf[4];
#pragma unroll
        for (int mt = 0; mt < 4; ++mt)
            af[mt] = *(const short8*)&Ab[(wr * 64 + mt * 16 + qm) * 32 + quad * 8];
#pragma unroll
        for (int nt = 0; nt < 4; ++nt)
            bf[nt] = *(const short8*)&Bb[(wc * 64 + nt * 16 + qm) * 32 + quad * 8];
#pragma unroll
        for (int mt = 0; mt < 4; ++mt)
#pragma unroll
            for (int nt = 0; nt < 4; ++nt)
                acc[mt][nt] = __builtin_amdgcn_mfma_f32_16x16x32_bf16(af[mt], bf[nt], acc[mt][nt], 0, 0, 0);
        __syncthreads();
    }

    const int whichB = n0 >> 8;   // bx 0,1 -> q; 2,3 -> k; 4,5 -> v
#pragma unroll
    for (int mt = 0; mt < 4; ++mt) {
#pragma unroll
        for (int r = 0; r < 4; ++r) {
            int m = m0 + wr * 64 + mt * 16 + quad * 4 + r;
            int b = (m >= NPOS) ? 1 : 0;
            int pos = m - b * NPOS;
            float c0 = 0.f, s0 = 0.f, c1 = 0.f, s1 = 0.f;
            if (whichB < 2) {
                float2 t0 = *(const float2*)&ropeT[(pos * 16 + (qm >> 1)) * 2];
                float2 t1 = *(const float2*)&ropeT[(pos * 16 + 8 + (qm >> 1)) * 2];
                c0 = t0.x; s0 = t0.y; c1 = t1.x; s1 = t1.y;
            }
#pragma unroll
            for (int nt = 0; nt < 4; ++nt) {
                int c = n0 + wc * 64 + nt * 16 + qm;
                int head = (c >> 5) & 7;
                int d = (nt & 1) * 16 + qm;
                float val = acc[mt][nt][r];
                if (whichB < 2) {
                    float other = __shfl_xor(val, 1);   // d parity == lane parity
                    float cf = (nt & 1) ? c1 : c0, sf = (nt & 1) ? s1 : s0;
                    val = (lane & 1) ? (val * cf + other * sf)
                                     : (val * cf - other * sf);
                }
                if (whichB == 0) {
                    qa[(size_t)m * 256 + head * 32 + d] = val;
                } else {
                    ushort* dst = (whichB == 1) ? kws : vws;
                    dst[(size_t)(((b << 3) + head) * NPOS + pos) * 32 + d] = f2b(val);
                }
            }
        }
    }
}

// Projection 64x64 tiles, in-place on d_out, B via global_load_lds.
// grid (4, 98)
__global__ __launch_bounds__(256) void proj_fast(
    const ushort* __restrict__ wprojT, const float* __restrict__ bias, float* out)
{
    __shared__ ushort Ap[64 * 264];
    __shared__ ushort Bb[64 * 32];
    const int t = threadIdx.x;
    const int lane = t & 63, wv = t >> 6;
    const int qm = lane & 15, quad = lane >> 4;
    const int n0 = blockIdx.x * 64, m0 = blockIdx.y * 64;
    const int wr = wv >> 1, wc = wv & 1;
    const int srow = lane >> 2, scol = (lane & 3) * 8;

    {   // stage own 64 fp32 rows -> bf16 LDS (before any write: in-place safe)
        int row = t >> 2, cb = (t & 3) * 64;
        const float4* src = (const float4*)&out[(size_t)(m0 + row) * 256 + cb];
#pragma unroll
        for (int i = 0; i < 16; ++i) {
            float4 v = src[i];
            ushort4 h; h.x = f2b(v.x); h.y = f2b(v.y); h.z = f2b(v.z); h.w = f2b(v.w);
            *(ushort4*)&Ap[row * 264 + cb + i * 4] = h;
        }
    }

    floatx4 acc[2][2];
#pragma unroll
    for (int i = 0; i < 2; ++i)
#pragma unroll
        for (int j = 0; j < 2; ++j) acc[i][j] = (floatx4){0.f, 0.f, 0.f, 0.f};

    for (int k0 = 0; k0 < 256; k0 += 32) {
        int rbase = wv * 16;
        async16(&wprojT[(size_t)(n0 + rbase + srow) * 256 + k0 + scol], &Bb[rbase * 32]);
        __syncthreads();
        short8 af[2], bf[2];
#pragma unroll
        for (int mt = 0; mt < 2; ++mt)
            af[mt] = *(const short8*)&Ap[(wr * 32 + mt * 16 + qm) * 264 + k0 + quad * 8];
#pragma unroll
        for (int nt = 0; nt < 2; ++nt)
            bf[nt] = *(const short8*)&Bb[(wc * 32 + nt * 16 + qm) * 32 + quad * 8];
#pragma unroll
        for (int mt = 0; mt < 2; ++mt)
#pragma unroll
            for (int nt = 0; nt < 2; ++nt)
                acc[mt][nt] = __builtin_amdgcn_mfma_f32_16x16x32_bf16(af[mt], bf[nt], acc[mt][nt], 0, 0, 0);
        __syncthreads();
    }

#pragma unroll
    for (int nt = 0; nt < 2; ++nt) {
        int c = n0 + wc * 32 + nt * 16 + qm;
        float bv = bias[c];
#pragma unroll
        for (int mt = 0; mt < 2; ++mt) {
#pragma unroll
            for (int r = 0; r < 4; ++r) {
                int m = m0 + wr * 32 + mt * 16 + quad * 4 + r;
                out[(size_t)m * 256 + c] = acc[mt][nt][r] + bv;
            }
        }
    }
}

// ===========================================================================
// Neighborhood attention (shared by both paths), uint4-vectorized LDS reads.
// ===========================================================================
__global__ __launch_bounds__(256) void nattn(
    const ushort* __restrict__ kws, const ushort* __restrict__ vws, float* qa)
{
    __shared__ ushort Ksm[196 * 32];
    __shared__ ushort Vsm[196 * 32];
    const int t = threadIdx.x;
    const int bh = blockIdx.y;
    const int b = bh >> 3, head = bh & 7;
    const int ti = blockIdx.x / 7, tj = blockIdx.x % 7;
    const int ty0 = ti * 8, tx0 = tj * 8;
    const int r0 = min(max(ty0 - 3, 0), HH - 14);
    const int c0 = min(max(tx0 - 3, 0), WW - 14);
    const ushort* kbase = kws + (size_t)bh * NPOS * 32;
    const ushort* vbase = vws + (size_t)bh * NPOS * 32;

    for (int idx = t; idx < 196 * 4; idx += 256) {
        int p = idx >> 2, ch = idx & 3;
        int g = ((r0 + p / 14) * WW + (c0 + p % 14)) * 32 + ch * 8;
        *(uint4*)&Ksm[p * 32 + ch * 8] = *(const uint4*)&kbase[g];
        *(uint4*)&Vsm[p * 32 + ch * 8] = *(const uint4*)&vbase[g];
    }
    __syncthreads();

    const int lane = t & 63, wv = t >> 6;
    const int qsub = lane & 15, part = lane >> 4;
    const int qi = wv * 16 + qsub;
    const int qy = ty0 + (qi >> 3), qx = tx0 + (qi & 7);
    const int pos = qy * WW + qx;
    float* qptr = qa + (size_t)(b * NPOS + pos) * 256 + head * 32;

    float qf[32];
#pragma unroll
    for (int c4 = 0; c4 < 8; ++c4) {
        float4 v = *(const float4*)&qptr[c4 * 4];
        qf[4 * c4] = v.x; qf[4 * c4 + 1] = v.y; qf[4 * c4 + 2] = v.z; qf[4 * c4 + 3] = v.w;
    }

    const int rs = min(max(qy - 3, 0), HH - 7) - r0;
    const int cs = min(max(qx - 3, 0), WW - 7) - c0;

    float sarr[13];
    float mx = -1e30f;
#pragma unroll
    for (int j = 0; j < 13; ++j) {
        int kk = part + 4 * j;
        sarr[j] = -1e30f;
        if (kk < 49) {
            int kp = (rs + kk / 7) * 14 + (cs + kk % 7);
            const uint4* Kp = (const uint4*)&Ksm[kp * 32];
            float s = 0.f;
#pragma unroll
            for (int c8 = 0; c8 < 4; ++c8) {
                uint4 u = Kp[c8];
                const float* qv = qf + 8 * c8;
                s += qv[0] * b2f((ushort)u.x) + qv[1] * b2f((ushort)(u.x >> 16));
                s += qv[2] * b2f((ushort)u.y) + qv[3] * b2f((ushort)(u.y >> 16));
                s += qv[4] * b2f((ushort)u.z) + qv[5] * b2f((ushort)(u.z >> 16));
                s += qv[6] * b2f((ushort)u.w) + qv[7] * b2f((ushort)(u.w >> 16));
            }
            s *= 0.17677669529663687f;  // 32^-0.5
            sarr[j] = s;
            mx = fmaxf(mx, s);
        }
    }
    mx = fmaxf(mx, __shfl_xor(mx, 16));
    mx = fmaxf(mx, __shfl_xor(mx, 32));

    float sum = 0.f;
    float facc[32];
#pragma unroll
    for (int c = 0; c < 32; ++c) facc[c] = 0.f;
#pragma unroll
    for (int j = 0; j < 13; ++j) {
        int kk = part + 4 * j;
        if (kk < 49) {
            float e = __expf(sarr[j] - mx);
            sum += e;
            int kp = (rs + kk / 7) * 14 + (cs + kk % 7);
            const uint4* Vp = (const uint4*)&Vsm[kp * 32];
#pragma unroll
            for (int c8 = 0; c8 < 4; ++c8) {
                uint4 u = Vp[c8];
                float* fv = facc + 8 * c8;
                fv[0] += e * b2f((ushort)u.x); fv[1] += e * b2f((ushort)(u.x >> 16));
                fv[2] += e * b2f((ushort)u.y); fv[3] += e * b2f((ushort)(u.y >> 16));
                fv[4] += e * b2f((ushort)u.z); fv[5] += e * b2f((ushort)(u.z >> 16));
                fv[6] += e * b2f((ushort)u.w); fv[7] += e * b2f((ushort)(u.w >> 16));
            }
        }
    }
    sum += __shfl_xor(sum, 16);
    sum += __shfl_xor(sum, 32);
#pragma unroll
    for (int c = 0; c < 32; ++c) {
        facc[c] += __shfl_xor(facc[c], 16);
        facc[c] += __shfl_xor(facc[c], 32);
    }

    if (part == 0) {
        float inv = 1.f / sum;
#pragma unroll
        for (int c4 = 0; c4 < 8; ++c4) {
            float4 o;
            o.x = facc[4 * c4]     * inv;
            o.y = facc[4 * c4 + 1] * inv;
            o.z = facc[4 * c4 + 2] * inv;
            o.w = facc[4 * c4 + 3] * inv;
            *(float4*)&qptr[c4 * 4] = o;
        }
    }
}

// ===========================================================================
// FALLBACK PATH (r8 kernels, verified passing)
// ===========================================================================
__global__ __launch_bounds__(256) void qkv_fb(
    const float* __restrict__ x, const float* __restrict__ w,
    float* __restrict__ qa, ushort* __restrict__ kws, ushort* __restrict__ vws)
{
    __shared__ ushort Asm[64 * 40];
    __shared__ ushort Bsm[64 * 40];
    const int t = threadIdx.x;
    const int m0 = blockIdx.y * 64;
    const int n0 = blockIdx.x * 64;
    const int lane = t & 63, wv = t >> 6;
    const int qm = lane & 15, quad = lane >> 4;

    floatx4 acc[4];
#pragma unroll
    for (int i = 0; i < 4; ++i) acc[i] = (floatx4){0.f, 0.f, 0.f, 0.f};

    for (int k0 = 0; k0 < 256; k0 += 32) {
#pragma unroll
        for (int i = 0; i < 2; ++i) {
            int p = t + 256 * i;
            int row = p >> 3, f4 = p & 7;
            float4 v = *(const float4*)&x[(size_t)(m0 + row) * 256 + k0 + f4 * 4];
            ushort4 h;
            h.x = f2b(v.x); h.y = f2b(v.y); h.z = f2b(v.z); h.w = f2b(v.w);
            *(ushort4*)&Asm[row * 40 + f4 * 4] = h;
        }
#pragma unroll
        for (int i = 0; i < 8; ++i) {
            int e = t + 256 * i;
            int kk = e >> 6, nn = e & 63;
            Bsm[nn * 40 + kk] = f2b(w[(size_t)(k0 + kk) * 768 + n0 + nn]);
        }
        __syncthreads();
        short8 af = *(const short8*)&Asm[(wv * 16 + qm) * 40 + quad * 8];
#pragma unroll
        for (int nt = 0; nt < 4; ++nt) {
            short8 bf = *(const short8*)&Bsm[(nt * 16 + qm) * 40 + quad * 8];
            acc[nt] = __builtin_amdgcn_mfma_f32_16x16x32_bf16(af, bf, acc[nt], 0, 0, 0);
        }
        __syncthreads();
    }

    const int whichB = n0 >> 8;
#pragma unroll
    for (int r = 0; r < 4; ++r) {
        int m = m0 + wv * 16 + quad * 4 + r;
        int b = (m >= NPOS) ? 1 : 0;
        int pos = m - b * NPOS;
        float cf[2], sf[2];
        if (whichB < 2) {
            float posf = (float)pos;
            __sincosf(posf * INVF[qm >> 1], &sf[0], &cf[0]);
            __sincosf(posf * INVF[8 + (qm >> 1)], &sf[1], &cf[1]);
        }
#pragma unroll
        for (int nt = 0; nt < 4; ++nt) {
            int par = nt & 1;
            int d = par * 16 + qm;
            int head = ((n0 >> 5) & 7) + (nt >> 1);
            float val = acc[nt][r];
            if (whichB < 2) {
                float other = __shfl_xor(val, 1);
                val = (lane & 1) ? (val * cf[par] + other * sf[par])
                                 : (val * cf[par] - other * sf[par]);
            }
            if (whichB == 0) {
                qa[(size_t)m * 256 + head * 32 + d] = val;
            } else {
                ushort* dst = (whichB == 1) ? kws : vws;
                dst[(size_t)(((b << 3) + head) * NPOS + pos) * 32 + d] = f2b(val);
            }
        }
    }
}

__global__ __launch_bounds__(256) void proj_fb(
    const float* __restrict__ w, const float* __restrict__ bias, float* out)
{
    __shared__ ushort Apad[64 * 264];
    __shared__ ushort Bsm[256 * 40];
    const int t = threadIdx.x;
    const int m0 = blockIdx.x * 64;
    const int lane = t & 63, wv = t >> 6;
    const int qm = lane & 15, quad = lane >> 4;

    {
        int row = t >> 2, cb = (t & 3) * 64;
        const float4* src = (const float4*)&out[(size_t)(m0 + row) * 256 + cb];
#pragma unroll
        for (int i = 0; i < 16; ++i) {
            float4 v = src[i];
            ushort4 h;
            h.x = f2b(v.x); h.y = f2b(v.y); h.z = f2b(v.z); h.w = f2b(v.w);
            *(ushort4*)&Apad[row * 264 + cb + i * 4] = h;
        }
    }

    floatx4 acc[4][4];
#pragma unroll
    for (int i = 0; i < 4; ++i)
#pragma unroll
        for (int j = 0; j < 4; ++j) acc[i][j] = (floatx4){0.f, 0.f, 0.f, 0.f};

    __syncthreads();

    for (int k0 = 0; k0 < 256; k0 += 32) {
#pragma unroll
        for (int i = 0; i < 32; ++i) {
            int e = t + 256 * i;
            int kk = e >> 8, nn = e & 255;
            Bsm[nn * 40 + kk] = f2b(w[(size_t)(k0 + kk) * 256 + nn]);
        }
        __syncthreads();
        short8 af[4];
#pragma unroll
        for (int mt = 0; mt < 4; ++mt)
            af[mt] = *(const short8*)&Apad[(mt * 16 + qm) * 264 + k0 + quad * 8];
#pragma unroll
        for (int nt = 0; nt < 4; ++nt) {
            short8 bf = *(const short8*)&Bsm[(wv * 64 + nt * 16 + qm) * 40 + quad * 8];
#pragma unroll
            for (int mt = 0; mt < 4; ++mt)
                acc[mt][nt] = __builtin_amdgcn_mfma_f32_16x16x32_bf16(af[mt], bf, acc[mt][nt], 0, 0, 0);
        }
        __syncthreads();
    }

#pragma unroll
    for (int nt = 0; nt < 4; ++nt) {
        int c = wv * 64 + nt * 16 + qm;
        float bv = bias[c];
#pragma unroll
        for (int mt = 0; mt < 4; ++mt) {
#pragma unroll
            for (int r = 0; r < 4; ++r) {
                int m = m0 + mt * 16 + quad * 4 + r;
                out[(size_t)m * 256 + c] = acc[mt][nt][r] + bv;
            }
        }
    }
}

// ===========================================================================
extern "C" void kernel_launch(void* const* d_in, const int* in_sizes, int n_in,
                              void* d_out, int out_size, void* d_ws, size_t ws_size,
                              hipStream_t stream)
{
    const float* x     = (const float*)d_in[0];
    const float* wqkv  = (const float*)d_in[1];
    const float* wproj = (const float*)d_in[2];
    const float* bproj = (const float*)d_in[3];
    float* out = (float*)d_out;
    char* ws = (char*)d_ws;

    // fast-path ws layout (bytes):
    //   xb      3,211,264  @ 0
    //   wqkvT     393,216  @ 3,211,264
    //   wprojT    131,072  @ 3,604,480
    //   ropeT     401,408  @ 3,735,552
    //   kws     3,211,264  @ 4,136,960
    //   vws     3,211,264  @ 7,348,224   -> total 10,559,488
    if (ws_size >= 10559488ull) {
        ushort* xb     = (ushort*)(ws);
        ushort* wqkvT  = (ushort*)(ws + 3211264);
        ushort* wprojT = (ushort*)(ws + 3604480);
        float*  ropeT  = (float*) (ws + 3735552);
        ushort* kws    = (ushort*)(ws + 4136960);
        ushort* vws    = (ushort*)(ws + 7348224);

        hipLaunchKernelGGL(prepass, dim3(1828), dim3(256), 0, stream,
                           x, wqkv, wproj, xb, wqkvT, wprojT, ropeT);
        hipLaunchKernelGGL(qkv_fast, dim3(6, 49), dim3(256), 0, stream,
                           xb, wqkvT, ropeT, out, kws, vws);
        hipLaunchKernelGGL(nattn, dim3(49, BATCH * HEADS), dim3(256), 0, stream,
                           kws, vws, out);
        hipLaunchKernelGGL(proj_fast, dim3(4, 98), dim3(256), 0, stream,
                           wprojT, bproj, out);
    } else {
        ushort* kws = (ushort*)ws;
        ushort* vws = (ushort*)(ws + 3211264);
        hipLaunchKernelGGL(qkv_fb, dim3(12, 98), dim3(256), 0, stream,
                           x, wqkv, out, kws, vws);
        hipLaunchKernelGGL(nattn, dim3(49, BATCH * HEADS), dim3(256), 0, stream,
                           kws, vws, out);
        hipLaunchKernelGGL(proj_fb, dim3(98), dim3(256), 0, stream,
                           wproj, bproj, out);
    }
}

// Round 10
// 130.282 us; speedup vs baseline: 1.1055x; 1.0629x over previous
//
#include <hip/hip_runtime.h>
#include <hip/hip_bf16.h>

#define HH 56
#define WW 56
#define NPOS 3136
#define BATCH 2
#define HEADS 8

typedef __attribute__((ext_vector_type(4))) float floatx4;
typedef __attribute__((ext_vector_type(8))) short short8;

static __device__ __forceinline__ ushort f2b(float f) {
    __hip_bfloat16 h = __float2bfloat16(f);
    return *reinterpret_cast<ushort*>(&h);
}
static __device__ __forceinline__ float b2f(ushort u) {
    return __uint_as_float(((uint)u) << 16);
}

// async global->LDS, 16B per lane. LDS dest = wave-uniform base + lane*16.
static __device__ __forceinline__ void async16(const ushort* g, ushort* l) {
    __builtin_amdgcn_global_load_lds(
        (const __attribute__((address_space(1))) unsigned int*)g,
        (__attribute__((address_space(3))) unsigned int*)l, 16, 0, 0);
}

// fl32(10^(-j/4)) == np.float32 inv-freq table
__constant__ float INVF[16] = {
    1.0f,   0.5623413251903491f,   0.31622776601683794f,   0.17782794100389228f,
    0.1f,   0.05623413251903491f,  0.031622776601683794f,  0.017782794100389228f,
    0.01f,  0.005623413251903491f, 0.0031622776601683794f, 0.0017782794100389228f,
    0.001f, 0.0005623413251903491f,0.00031622776601683794f,0.00017782794100389228f
};

// ===========================================================================
// FAST PATH
// ===========================================================================

// Prepass (lean): rope table (196) + wqkvT (48) + wprojT (16) = 260 blocks.
__global__ __launch_bounds__(256) void prep(
    const float* __restrict__ wqkv, const float* __restrict__ wproj,
    ushort* __restrict__ wqkvT, ushort* __restrict__ wprojT,
    float* __restrict__ ropeT)
{
    __shared__ ushort Ls[64 * 65];
    const int bid = blockIdx.x, t = threadIdx.x;
    if (bid < 196) {                        // rope table [pos][16] (cos,sin)
        int i = bid * 256 + t;
        int pos = i >> 4, pr = i & 15;
        float s, c;
        __sincosf((float)pos * INVF[pr], &s, &c);
        ropeT[2 * i] = c; ropeT[2 * i + 1] = s;
    } else if (bid < 244) {                 // wqkv (256,768) -> wqkvT (768,256)
        int l = bid - 196;
        int nb = (l % 12) * 64, kb = (l / 12) * 64;
#pragma unroll
        for (int i = 0; i < 16; ++i) {
            int e = t + 256 * i, kk = e >> 6, nn = e & 63;
            Ls[kk * 65 + nn] = f2b(wqkv[(size_t)(kb + kk) * 768 + nb + nn]);
        }
        __syncthreads();
#pragma unroll
        for (int i = 0; i < 16; ++i) {
            int e = t + 256 * i, nn = e >> 6, kk = e & 63;
            wqkvT[(size_t)(nb + nn) * 256 + kb + kk] = Ls[kk * 65 + nn];
        }
    } else {                                // wproj (256,256) -> wprojT
        int l = bid - 244;
        int nb = (l & 3) * 64, kb = (l >> 2) * 64;
#pragma unroll
        for (int i = 0; i < 16; ++i) {
            int e = t + 256 * i, kk = e >> 6, nn = e & 63;
            Ls[kk * 65 + nn] = f2b(wproj[(size_t)(kb + kk) * 256 + nb + nn]);
        }
        __syncthreads();
#pragma unroll
        for (int i = 0; i < 16; ++i) {
            int e = t + 256 * i, nn = e >> 6, kk = e & 63;
            wprojT[(size_t)(nb + nn) * 256 + kb + kk] = Ls[kk * 65 + nn];
        }
    }
}

// QKV GEMM 128x128 tile. A staged from fp32 x via VGPR cvt; B via
// global_load_lds from bf16 wqkvT. q/k/v all bf16 -> ws. grid (6, 49).
__global__ __launch_bounds__(256) void qkv_fast(
    const float* __restrict__ x, const ushort* __restrict__ wqkvT,
    const float* __restrict__ ropeT,
    ushort* __restrict__ qb, ushort* __restrict__ kws, ushort* __restrict__ vws)
{
    __shared__ ushort Ab[128 * 32];
    __shared__ ushort Bb[128 * 32];
    const int t = threadIdx.x;
    const int lane = t & 63, wv = t >> 6;
    const int qm = lane & 15, quad = lane >> 4;
    const int m0 = blockIdx.y * 128, n0 = blockIdx.x * 128;
    const int wr = wv >> 1, wc = wv & 1;
    const int srow = lane >> 2, scol = (lane & 3) * 8;
    const int arow = t >> 1, aseg = (t & 1) * 16;

    floatx4 acc[4][4];
#pragma unroll
    for (int i = 0; i < 4; ++i)
#pragma unroll
        for (int j = 0; j < 4; ++j) acc[i][j] = (floatx4){0.f, 0.f, 0.f, 0.f};

    for (int k0 = 0; k0 < 256; k0 += 32) {
        // A: 128x32 fp32 -> bf16 (4 float4 + cvt per thread)
#pragma unroll
        for (int i = 0; i < 4; ++i) {
            int col = aseg + i * 4;
            float4 v = *(const float4*)&x[(size_t)(m0 + arow) * 256 + k0 + col];
            ushort4 h; h.x = f2b(v.x); h.y = f2b(v.y); h.z = f2b(v.z); h.w = f2b(v.w);
            *(ushort4*)&Ab[arow * 32 + col] = h;
        }
        // B: async 16B/lane from pre-transposed bf16 weights
#pragma unroll
        for (int j = 0; j < 2; ++j) {
            int rbase = wv * 32 + j * 16;
            async16(&wqkvT[(size_t)(n0 + rbase + srow) * 256 + k0 + scol], &Bb[rbase * 32]);
        }
        __syncthreads();
        short8 af[4], bf[4];
#pragma unroll
        for (int mt = 0; mt < 4; ++mt)
            af[mt] = *(const short8*)&Ab[(wr * 64 + mt * 16 + qm) * 32 + quad * 8];
#pragma unroll
        for (int nt = 0; nt < 4; ++nt)
            bf[nt] = *(const short8*)&Bb[(wc * 64 + nt * 16 + qm) * 32 + quad * 8];
#pragma unroll
        for (int mt = 0; mt < 4; ++mt)
#pragma unroll
            for (int nt = 0; nt < 4; ++nt)
                acc[mt][nt] = __builtin_amdgcn_mfma_f32_16x16x32_bf16(af[mt], bf[nt], acc[mt][nt], 0, 0, 0);
        __syncthreads();
    }

    const int whichB = n0 >> 8;   // bx 0,1 -> q; 2,3 -> k; 4,5 -> v
#pragma unroll
    for (int mt = 0; mt < 4; ++mt) {
#pragma unroll
        for (int r = 0; r < 4; ++r) {
            int m = m0 + wr * 64 + mt * 16 + quad * 4 + r;
            int b = (m >= NPOS) ? 1 : 0;
            int pos = m - b * NPOS;
            float c0 = 0.f, s0 = 0.f, c1 = 0.f, s1 = 0.f;
            if (whichB < 2) {
                float2 t0 = *(const float2*)&ropeT[(pos * 16 + (qm >> 1)) * 2];
                float2 t1 = *(const float2*)&ropeT[(pos * 16 + 8 + (qm >> 1)) * 2];
                c0 = t0.x; s0 = t0.y; c1 = t1.x; s1 = t1.y;
            }
#pragma unroll
            for (int nt = 0; nt < 4; ++nt) {
                int c = n0 + wc * 64 + nt * 16 + qm;
                int head = (c >> 5) & 7;
                int d = (nt & 1) * 16 + qm;
                float val = acc[mt][nt][r];
                if (whichB < 2) {
                    float other = __shfl_xor(val, 1);   // d parity == lane parity
                    float cf = (nt & 1) ? c1 : c0, sf = (nt & 1) ? s1 : s0;
                    val = (lane & 1) ? (val * cf + other * sf)
                                     : (val * cf - other * sf);
                }
                if (whichB == 0) {
                    qb[(size_t)m * 256 + head * 32 + d] = f2b(val);
                } else {
                    ushort* dst = (whichB == 1) ? kws : vws;
                    dst[(size_t)(((b << 3) + head) * NPOS + pos) * 32 + d] = f2b(val);
                }
            }
        }
    }
}

// Neighborhood attention: bf16 q in, bf16 attn out (both in ws).
__global__ __launch_bounds__(256) void nattn(
    const ushort* __restrict__ kws, const ushort* __restrict__ vws,
    const ushort* __restrict__ qb, ushort* __restrict__ ab)
{
    __shared__ ushort Ksm[196 * 32];
    __shared__ ushort Vsm[196 * 32];
    const int t = threadIdx.x;
    const int bh = blockIdx.y;
    const int b = bh >> 3, head = bh & 7;
    const int ti = blockIdx.x / 7, tj = blockIdx.x % 7;
    const int ty0 = ti * 8, tx0 = tj * 8;
    const int r0 = min(max(ty0 - 3, 0), HH - 14);
    const int c0 = min(max(tx0 - 3, 0), WW - 14);
    const ushort* kbase = kws + (size_t)bh * NPOS * 32;
    const ushort* vbase = vws + (size_t)bh * NPOS * 32;

    for (int idx = t; idx < 196 * 4; idx += 256) {
        int p = idx >> 2, ch = idx & 3;
        int g = ((r0 + p / 14) * WW + (c0 + p % 14)) * 32 + ch * 8;
        *(uint4*)&Ksm[p * 32 + ch * 8] = *(const uint4*)&kbase[g];
        *(uint4*)&Vsm[p * 32 + ch * 8] = *(const uint4*)&vbase[g];
    }
    __syncthreads();

    const int lane = t & 63, wv = t >> 6;
    const int qsub = lane & 15, part = lane >> 4;
    const int qi = wv * 16 + qsub;
    const int qy = ty0 + (qi >> 3), qx = tx0 + (qi & 7);
    const int pos = qy * WW + qx;
    const size_t qoff = (size_t)(b * NPOS + pos) * 256 + head * 32;

    float qf[32];
    {
        const uint* q4 = (const uint*)(qb + qoff);
#pragma unroll
        for (int c2 = 0; c2 < 16; ++c2) {
            uint u = q4[c2];
            qf[2 * c2] = b2f((ushort)u); qf[2 * c2 + 1] = b2f((ushort)(u >> 16));
        }
    }

    const int rs = min(max(qy - 3, 0), HH - 7) - r0;
    const int cs = min(max(qx - 3, 0), WW - 7) - c0;

    float sarr[13];
    float mx = -1e30f;
#pragma unroll
    for (int j = 0; j < 13; ++j) {
        int kk = part + 4 * j;
        sarr[j] = -1e30f;
        if (kk < 49) {
            int kp = (rs + kk / 7) * 14 + (cs + kk % 7);
            const uint4* Kp = (const uint4*)&Ksm[kp * 32];
            float s = 0.f;
#pragma unroll
            for (int c8 = 0; c8 < 4; ++c8) {
                uint4 u = Kp[c8];
                const float* qv = qf + 8 * c8;
                s += qv[0] * b2f((ushort)u.x) + qv[1] * b2f((ushort)(u.x >> 16));
                s += qv[2] * b2f((ushort)u.y) + qv[3] * b2f((ushort)(u.y >> 16));
                s += qv[4] * b2f((ushort)u.z) + qv[5] * b2f((ushort)(u.z >> 16));
                s += qv[6] * b2f((ushort)u.w) + qv[7] * b2f((ushort)(u.w >> 16));
            }
            s *= 0.17677669529663687f;  // 32^-0.5
            sarr[j] = s;
            mx = fmaxf(mx, s);
        }
    }
    mx = fmaxf(mx, __shfl_xor(mx, 16));
    mx = fmaxf(mx, __shfl_xor(mx, 32));

    float sum = 0.f;
    float facc[32];
#pragma unroll
    for (int c = 0; c < 32; ++c) facc[c] = 0.f;
#pragma unroll
    for (int j = 0; j < 13; ++j) {
        int kk = part + 4 * j;
        if (kk < 49) {
            float e = __expf(sarr[j] - mx);
            sum += e;
            int kp = (rs + kk / 7) * 14 + (cs + kk % 7);
            const uint4* Vp = (const uint4*)&Vsm[kp * 32];
#pragma unroll
            for (int c8 = 0; c8 < 4; ++c8) {
                uint4 u = Vp[c8];
                float* fv = facc + 8 * c8;
                fv[0] += e * b2f((ushort)u.x); fv[1] += e * b2f((ushort)(u.x >> 16));
                fv[2] += e * b2f((ushort)u.y); fv[3] += e * b2f((ushort)(u.y >> 16));
                fv[4] += e * b2f((ushort)u.z); fv[5] += e * b2f((ushort)(u.z >> 16));
                fv[6] += e * b2f((ushort)u.w); fv[7] += e * b2f((ushort)(u.w >> 16));
            }
        }
    }
    sum += __shfl_xor(sum, 16);
    sum += __shfl_xor(sum, 32);
#pragma unroll
    for (int c = 0; c < 32; ++c) {
        facc[c] += __shfl_xor(facc[c], 16);
        facc[c] += __shfl_xor(facc[c], 32);
    }

    if (part == 0) {
        float inv = 1.f / sum;
        uint* op = (uint*)(ab + qoff);
#pragma unroll
        for (int c2 = 0; c2 < 16; ++c2) {
            uint lo = f2b(facc[2 * c2] * inv);
            uint hi = f2b(facc[2 * c2 + 1] * inv);
            op[c2] = lo | (hi << 16);
        }
    }
}

// Projection 64x64 tiles; A (attn bf16) and B (wprojT) both via async16.
// Writes d_out fp32 (sole writer). grid (4, 98).
__global__ __launch_bounds__(256) void proj_fast(
    const ushort* __restrict__ ab, const ushort* __restrict__ wprojT,
    const float* __restrict__ bias, float* __restrict__ out)
{
    __shared__ ushort Ap[64 * 32];
    __shared__ ushort Bp[64 * 32];
    const int t = threadIdx.x;
    const int lane = t & 63, wv = t >> 6;
    const int qm = lane & 15, quad = lane >> 4;
    const int n0 = blockIdx.x * 64, m0 = blockIdx.y * 64;
    const int wr = wv >> 1, wc = wv & 1;
    const int srow = lane >> 2, scol = (lane & 3) * 8;

    floatx4 acc[2][2];
#pragma unroll
    for (int i = 0; i < 2; ++i)
#pragma unroll
        for (int j = 0; j < 2; ++j) acc[i][j] = (floatx4){0.f, 0.f, 0.f, 0.f};

    for (int k0 = 0; k0 < 256; k0 += 32) {
        int rbase = wv * 16;
        async16(&ab[(size_t)(m0 + rbase + srow) * 256 + k0 + scol], &Ap[rbase * 32]);
        async16(&wprojT[(size_t)(n0 + rbase + srow) * 256 + k0 + scol], &Bp[rbase * 32]);
        __syncthreads();
        short8 af[2], bf[2];
#pragma unroll
        for (int mt = 0; mt < 2; ++mt)
            af[mt] = *(const short8*)&Ap[(wr * 32 + mt * 16 + qm) * 32 + quad * 8];
#pragma unroll
        for (int nt = 0; nt < 2; ++nt)
            bf[nt] = *(const short8*)&Bp[(wc * 32 + nt * 16 + qm) * 32 + quad * 8];
#pragma unroll
        for (int mt = 0; mt < 2; ++mt)
#pragma unroll
            for (int nt = 0; nt < 2; ++nt)
                acc[mt][nt] = __builtin_amdgcn_mfma_f32_16x16x32_bf16(af[mt], bf[nt], acc[mt][nt], 0, 0, 0);
        __syncthreads();
    }

#pragma unroll
    for (int nt = 0; nt < 2; ++nt) {
        int c = n0 + wc * 32 + nt * 16 + qm;
        float bv = bias[c];
#pragma unroll
        for (int mt = 0; mt < 2; ++mt) {
#pragma unroll
            for (int r = 0; r < 4; ++r) {
                int m = m0 + wr * 32 + mt * 16 + quad * 4 + r;
                out[(size_t)m * 256 + c] = acc[mt][nt][r] + bv;
            }
        }
    }
}

// ===========================================================================
// FALLBACK PATH (r8 kernels, verified passing; used only if ws too small)
// ===========================================================================
__global__ __launch_bounds__(256) void qkv_fb(
    const float* __restrict__ x, const float* __restrict__ w,
    float* __restrict__ qa, ushort* __restrict__ kws, ushort* __restrict__ vws)
{
    __shared__ ushort Asm[64 * 40];
    __shared__ ushort Bsm[64 * 40];
    const int t = threadIdx.x;
    const int m0 = blockIdx.y * 64;
    const int n0 = blockIdx.x * 64;
    const int lane = t & 63, wv = t >> 6;
    const int qm = lane & 15, quad = lane >> 4;

    floatx4 acc[4];
#pragma unroll
    for (int i = 0; i < 4; ++i) acc[i] = (floatx4){0.f, 0.f, 0.f, 0.f};

    for (int k0 = 0; k0 < 256; k0 += 32) {
#pragma unroll
        for (int i = 0; i < 2; ++i) {
            int p = t + 256 * i;
            int row = p >> 3, f4 = p & 7;
            float4 v = *(const float4*)&x[(size_t)(m0 + row) * 256 + k0 + f4 * 4];
            ushort4 h;
            h.x = f2b(v.x); h.y = f2b(v.y); h.z = f2b(v.z); h.w = f2b(v.w);
            *(ushort4*)&Asm[row * 40 + f4 * 4] = h;
        }
#pragma unroll
        for (int i = 0; i < 8; ++i) {
            int e = t + 256 * i;
            int kk = e >> 6, nn = e & 63;
            Bsm[nn * 40 + kk] = f2b(w[(size_t)(k0 + kk) * 768 + n0 + nn]);
        }
        __syncthreads();
        short8 af = *(const short8*)&Asm[(wv * 16 + qm) * 40 + quad * 8];
#pragma unroll
        for (int nt = 0; nt < 4; ++nt) {
            short8 bf = *(const short8*)&Bsm[(nt * 16 + qm) * 40 + quad * 8];
            acc[nt] = __builtin_amdgcn_mfma_f32_16x16x32_bf16(af, bf, acc[nt], 0, 0, 0);
        }
        __syncthreads();
    }

    const int whichB = n0 >> 8;
#pragma unroll
    for (int r = 0; r < 4; ++r) {
        int m = m0 + wv * 16 + quad * 4 + r;
        int b = (m >= NPOS) ? 1 : 0;
        int pos = m - b * NPOS;
        float cf[2], sf[2];
        if (whichB < 2) {
            float posf = (float)pos;
            __sincosf(posf * INVF[qm >> 1], &sf[0], &cf[0]);
            __sincosf(posf * INVF[8 + (qm >> 1)], &sf[1], &cf[1]);
        }
#pragma unroll
        for (int nt = 0; nt < 4; ++nt) {
            int par = nt & 1;
            int d = par * 16 + qm;
            int head = ((n0 >> 5) & 7) + (nt >> 1);
            float val = acc[nt][r];
            if (whichB < 2) {
                float other = __shfl_xor(val, 1);
                val = (lane & 1) ? (val * cf[par] + other * sf[par])
                                 : (val * cf[par] - other * sf[par]);
            }
            if (whichB == 0) {
                qa[(size_t)m * 256 + head * 32 + d] = val;
            } else {
                ushort* dst = (whichB == 1) ? kws : vws;
                dst[(size_t)(((b << 3) + head) * NPOS + pos) * 32 + d] = f2b(val);
            }
        }
    }
}

__global__ __launch_bounds__(256) void nattn_fb(
    const ushort* __restrict__ kws, const ushort* __restrict__ vws, float* qa)
{
    __shared__ ushort Ksm[196 * 32];
    __shared__ ushort Vsm[196 * 32];
    const int t = threadIdx.x;
    const int bh = blockIdx.y;
    const int b = bh >> 3, head = bh & 7;
    const int ti = blockIdx.x / 7, tj = blockIdx.x % 7;
    const int ty0 = ti * 8, tx0 = tj * 8;
    const int r0 = min(max(ty0 - 3, 0), HH - 14);
    const int c0 = min(max(tx0 - 3, 0), WW - 14);
    const ushort* kbase = kws + (size_t)bh * NPOS * 32;
    const ushort* vbase = vws + (size_t)bh * NPOS * 32;

    for (int idx = t; idx < 196 * 4; idx += 256) {
        int p = idx >> 2, ch = idx & 3;
        int g = ((r0 + p / 14) * WW + (c0 + p % 14)) * 32 + ch * 8;
        *(uint4*)&Ksm[p * 32 + ch * 8] = *(const uint4*)&kbase[g];
        *(uint4*)&Vsm[p * 32 + ch * 8] = *(const uint4*)&vbase[g];
    }
    __syncthreads();

    const int lane = t & 63, wv = t >> 6;
    const int qsub = lane & 15, part = lane >> 4;
    const int qi = wv * 16 + qsub;
    const int qy = ty0 + (qi >> 3), qx = tx0 + (qi & 7);
    const int pos = qy * WW + qx;
    float* qptr = qa + (size_t)(b * NPOS + pos) * 256 + head * 32;

    float qf[32];
#pragma unroll
    for (int c4 = 0; c4 < 8; ++c4) {
        float4 v = *(const float4*)&qptr[c4 * 4];
        qf[4 * c4] = v.x; qf[4 * c4 + 1] = v.y; qf[4 * c4 + 2] = v.z; qf[4 * c4 + 3] = v.w;
    }

    const int rs = min(max(qy - 3, 0), HH - 7) - r0;
    const int cs = min(max(qx - 3, 0), WW - 7) - c0;

    float sarr[13];
    float mx = -1e30f;
#pragma unroll
    for (int j = 0; j < 13; ++j) {
        int kk = part + 4 * j;
        sarr[j] = -1e30f;
        if (kk < 49) {
            int kp = (rs + kk / 7) * 14 + (cs + kk % 7);
            const uint4* Kp = (const uint4*)&Ksm[kp * 32];
            float s = 0.f;
#pragma unroll
            for (int c8 = 0; c8 < 4; ++c8) {
                uint4 u = Kp[c8];
                const float* qv = qf + 8 * c8;
                s += qv[0] * b2f((ushort)u.x) + qv[1] * b2f((ushort)(u.x >> 16));
                s += qv[2] * b2f((ushort)u.y) + qv[3] * b2f((ushort)(u.y >> 16));
                s += qv[4] * b2f((ushort)u.z) + qv[5] * b2f((ushort)(u.z >> 16));
                s += qv[6] * b2f((ushort)u.w) + qv[7] * b2f((ushort)(u.w >> 16));
            }
            s *= 0.17677669529663687f;
            sarr[j] = s;
            mx = fmaxf(mx, s);
        }
    }
    mx = fmaxf(mx, __shfl_xor(mx, 16));
    mx = fmaxf(mx, __shfl_xor(mx, 32));

    float sum = 0.f;
    float facc[32];
#pragma unroll
    for (int c = 0; c < 32; ++c) facc[c] = 0.f;
#pragma unroll
    for (int j = 0; j < 13; ++j) {
        int kk = part + 4 * j;
        if (kk < 49) {
            float e = __expf(sarr[j] - mx);
            sum += e;
            int kp = (rs + kk / 7) * 14 + (cs + kk % 7);
            const uint4* Vp = (const uint4*)&Vsm[kp * 32];
#pragma unroll
            for (int c8 = 0; c8 < 4; ++c8) {
                uint4 u = Vp[c8];
                float* fv = facc + 8 * c8;
                fv[0] += e * b2f((ushort)u.x); fv[1] += e * b2f((ushort)(u.x >> 16));
                fv[2] += e * b2f((ushort)u.y); fv[3] += e * b2f((ushort)(u.y >> 16));
                fv[4] += e * b2f((ushort)u.z); fv[5] += e * b2f((ushort)(u.z >> 16));
                fv[6] += e * b2f((ushort)u.w); fv[7] += e * b2f((ushort)(u.w >> 16));
            }
        }
    }
    sum += __shfl_xor(sum, 16);
    sum += __shfl_xor(sum, 32);
#pragma unroll
    for (int c = 0; c < 32; ++c) {
        facc[c] += __shfl_xor(facc[c], 16);
        facc[c] += __shfl_xor(facc[c], 32);
    }

    if (part == 0) {
        float inv = 1.f / sum;
#pragma unroll
        for (int c4 = 0; c4 < 8; ++c4) {
            float4 o;
            o.x = facc[4 * c4] * inv; o.y = facc[4 * c4 + 1] * inv;
            o.z = facc[4 * c4 + 2] * inv; o.w = facc[4 * c4 + 3] * inv;
            *(float4*)&qptr[c4 * 4] = o;
        }
    }
}

__global__ __launch_bounds__(256) void proj_fb(
    const float* __restrict__ w, const float* __restrict__ bias, float* out)
{
    __shared__ ushort Apad[64 * 264];
    __shared__ ushort Bsm[256 * 40];
    const int t = threadIdx.x;
    const int m0 = blockIdx.x * 64;
    const int lane = t & 63, wv = t >> 6;
    const int qm = lane & 15, quad = lane >> 4;

    {
        int row = t >> 2, cb = (t & 3) * 64;
        const float4* src = (const float4*)&out[(size_t)(m0 + row) * 256 + cb];
#pragma unroll
        for (int i = 0; i < 16; ++i) {
            float4 v = src[i];
            ushort4 h;
            h.x = f2b(v.x); h.y = f2b(v.y); h.z = f2b(v.z); h.w = f2b(v.w);
            *(ushort4*)&Apad[row * 264 + cb + i * 4] = h;
        }
    }

    floatx4 acc[4][4];
#pragma unroll
    for (int i = 0; i < 4; ++i)
#pragma unroll
        for (int j = 0; j < 4; ++j) acc[i][j] = (floatx4){0.f, 0.f, 0.f, 0.f};

    __syncthreads();

    for (int k0 = 0; k0 < 256; k0 += 32) {
#pragma unroll
        for (int i = 0; i < 32; ++i) {
            int e = t + 256 * i;
            int kk = e >> 8, nn = e & 255;
            Bsm[nn * 40 + kk] = f2b(w[(size_t)(k0 + kk) * 256 + nn]);
        }
        __syncthreads();
        short8 af[4];
#pragma unroll
        for (int mt = 0; mt < 4; ++mt)
            af[mt] = *(const short8*)&Apad[(mt * 16 + qm) * 264 + k0 + quad * 8];
#pragma unroll
        for (int nt = 0; nt < 4; ++nt) {
            short8 bf = *(const short8*)&Bsm[(wv * 64 + nt * 16 + qm) * 40 + quad * 8];
#pragma unroll
            for (int mt = 0; mt < 4; ++mt)
                acc[mt][nt] = __builtin_amdgcn_mfma_f32_16x16x32_bf16(af[mt], bf, acc[mt][nt], 0, 0, 0);
        }
        __syncthreads();
    }

#pragma unroll
    for (int nt = 0; nt < 4; ++nt) {
        int c = wv * 64 + nt * 16 + qm;
        float bv = bias[c];
#pragma unroll
        for (int mt = 0; mt < 4; ++mt) {
#pragma unroll
            for (int r = 0; r < 4; ++r) {
                int m = m0 + mt * 16 + quad * 4 + r;
                out[(size_t)m * 256 + c] = acc[mt][nt][r] + bv;
            }
        }
    }
}

// ===========================================================================
extern "C" void kernel_launch(void* const* d_in, const int* in_sizes, int n_in,
                              void* d_out, int out_size, void* d_ws, size_t ws_size,
                              hipStream_t stream)
{
    const float* x     = (const float*)d_in[0];
    const float* wqkv  = (const float*)d_in[1];
    const float* wproj = (const float*)d_in[2];
    const float* bproj = (const float*)d_in[3];
    float* out = (float*)d_out;
    char* ws = (char*)d_ws;

    // fast-path ws layout (bytes):
    //   wqkvT   393,216 @ 0
    //   wprojT  131,072 @   393,216
    //   ropeT   401,408 @   524,288
    //   qb    3,211,264 @   925,696
    //   kws   3,211,264 @ 4,136,960
    //   vws   3,211,264 @ 7,348,224
    //   ab    3,211,264 @ 10,559,488   -> total 13,770,752
    if (ws_size >= 13770752ull) {
        ushort* wqkvT  = (ushort*)(ws);
        ushort* wprojT = (ushort*)(ws + 393216);
        float*  ropeT  = (float*) (ws + 524288);
        ushort* qb     = (ushort*)(ws + 925696);
        ushort* kws    = (ushort*)(ws + 4136960);
        ushort* vws    = (ushort*)(ws + 7348224);
        ushort* ab     = (ushort*)(ws + 10559488);

        hipLaunchKernelGGL(prep, dim3(260), dim3(256), 0, stream,
                           wqkv, wproj, wqkvT, wprojT, ropeT);
        hipLaunchKernelGGL(qkv_fast, dim3(6, 49), dim3(256), 0, stream,
                           x, wqkvT, ropeT, qb, kws, vws);
        hipLaunchKernelGGL(nattn, dim3(49, BATCH * HEADS), dim3(256), 0, stream,
                           kws, vws, qb, ab);
        hipLaunchKernelGGL(proj_fast, dim3(4, 98), dim3(256), 0, stream,
                           ab, wprojT, bproj, out);
    } else {
        ushort* kws = (ushort*)ws;
        ushort* vws = (ushort*)(ws + 3211264);
        hipLaunchKernelGGL(qkv_fb, dim3(12, 98), dim3(256), 0, stream,
                           x, wqkv, out, kws, vws);
        hipLaunchKernelGGL(nattn_fb, dim3(49, BATCH * HEADS), dim3(256), 0, stream,
                           kws, vws, out);
        hipLaunchKernelGGL(proj_fb, dim3(98), dim3(256), 0, stream,
                           wproj, bproj, out);
    }
}

// Round 11
// 115.280 us; speedup vs baseline: 1.2493x; 1.1301x over previous
//
#include <hip/hip_runtime.h>
#include <hip/hip_bf16.h>

#define HH 56
#define WW 56
#define NPOS 3136
#define BATCH 2
#define HEADS 8

typedef __attribute__((ext_vector_type(4))) float floatx4;
typedef __attribute__((ext_vector_type(8))) short short8;
typedef __attribute__((ext_vector_type(2))) _Float16 half2v;

static __device__ __forceinline__ ushort f2b(float f) {
    __hip_bfloat16 h = __float2bfloat16(f);
    return *reinterpret_cast<ushort*>(&h);
}
static __device__ __forceinline__ float b2f(ushort u) {
    return __uint_as_float(((uint)u) << 16);
}
static __device__ __forceinline__ ushort f2h(float f) {
    union { _Float16 h; ushort u; } c; c.h = (_Float16)f; return c.u;
}
static __device__ __forceinline__ half2v u2h2(uint u) {
    union { uint u; half2v h; } c; c.u = u; return c.h;
}

// async global->LDS, 16B per lane. LDS dest = wave-uniform base + lane*16.
static __device__ __forceinline__ void async16(const ushort* g, ushort* l) {
    __builtin_amdgcn_global_load_lds(
        (const __attribute__((address_space(1))) unsigned int*)g,
        (__attribute__((address_space(3))) unsigned int*)l, 16, 0, 0);
}

// fl32(10^(-j/4)) == np.float32 inv-freq table
__constant__ float INVF[16] = {
    1.0f,   0.5623413251903491f,   0.31622776601683794f,   0.17782794100389228f,
    0.1f,   0.05623413251903491f,  0.031622776601683794f,  0.017782794100389228f,
    0.01f,  0.005623413251903491f, 0.0031622776601683794f, 0.0017782794100389228f,
    0.001f, 0.0005623413251903491f,0.00031622776601683794f,0.00017782794100389228f
};

#define QSCALE 0.17677669529663687f   // 32^-0.5, folded into q at store

// ===========================================================================
// FAST PATH
// ===========================================================================

// Prepass: wqkvT (48 blocks) + wprojT (16 blocks) = 64 blocks.
__global__ __launch_bounds__(256) void prep(
    const float* __restrict__ wqkv, const float* __restrict__ wproj,
    ushort* __restrict__ wqkvT, ushort* __restrict__ wprojT)
{
    __shared__ ushort Ls[64 * 65];
    const int bid = blockIdx.x, t = threadIdx.x;
    if (bid < 48) {                         // wqkv (256,768) -> wqkvT (768,256)
        int nb = (bid % 12) * 64, kb = (bid / 12) * 64;
#pragma unroll
        for (int i = 0; i < 16; ++i) {
            int e = t + 256 * i, kk = e >> 6, nn = e & 63;
            Ls[kk * 65 + nn] = f2b(wqkv[(size_t)(kb + kk) * 768 + nb + nn]);
        }
        __syncthreads();
#pragma unroll
        for (int i = 0; i < 16; ++i) {
            int e = t + 256 * i, nn = e >> 6, kk = e & 63;
            wqkvT[(size_t)(nb + nn) * 256 + kb + kk] = Ls[kk * 65 + nn];
        }
    } else {                                // wproj (256,256) -> wprojT
        int l = bid - 48;
        int nb = (l & 3) * 64, kb = (l >> 2) * 64;
#pragma unroll
        for (int i = 0; i < 16; ++i) {
            int e = t + 256 * i, kk = e >> 6, nn = e & 63;
            Ls[kk * 65 + nn] = f2b(wproj[(size_t)(kb + kk) * 256 + nb + nn]);
        }
        __syncthreads();
#pragma unroll
        for (int i = 0; i < 16; ++i) {
            int e = t + 256 * i, nn = e >> 6, kk = e & 63;
            wprojT[(size_t)(nb + nn) * 256 + kb + kk] = Ls[kk * 65 + nn];
        }
    }
}

// QKV GEMM 128x128 tile. A cvt-staged from fp32 x; B async16 from bf16 wqkvT.
// Inline __sincosf RoPE. q (scaled) / k / v stored F16 -> ws. grid (6, 49).
__global__ __launch_bounds__(256) void qkv_fast(
    const float* __restrict__ x, const ushort* __restrict__ wqkvT,
    ushort* __restrict__ qb, ushort* __restrict__ kws, ushort* __restrict__ vws)
{
    __shared__ ushort Ab[128 * 32];
    __shared__ ushort Bb[128 * 32];
    const int t = threadIdx.x;
    const int lane = t & 63, wv = t >> 6;
    const int qm = lane & 15, quad = lane >> 4;
    const int m0 = blockIdx.y * 128, n0 = blockIdx.x * 128;
    const int wr = wv >> 1, wc = wv & 1;
    const int srow = lane >> 2, scol = (lane & 3) * 8;
    const int arow = t >> 1, aseg = (t & 1) * 16;

    floatx4 acc[4][4];
#pragma unroll
    for (int i = 0; i < 4; ++i)
#pragma unroll
        for (int j = 0; j < 4; ++j) acc[i][j] = (floatx4){0.f, 0.f, 0.f, 0.f};

    for (int k0 = 0; k0 < 256; k0 += 32) {
#pragma unroll
        for (int i = 0; i < 4; ++i) {
            int col = aseg + i * 4;
            float4 v = *(const float4*)&x[(size_t)(m0 + arow) * 256 + k0 + col];
            ushort4 h; h.x = f2b(v.x); h.y = f2b(v.y); h.z = f2b(v.z); h.w = f2b(v.w);
            *(ushort4*)&Ab[arow * 32 + col] = h;
        }
#pragma unroll
        for (int j = 0; j < 2; ++j) {
            int rbase = wv * 32 + j * 16;
            async16(&wqkvT[(size_t)(n0 + rbase + srow) * 256 + k0 + scol], &Bb[rbase * 32]);
        }
        __syncthreads();
        short8 af[4], bf[4];
#pragma unroll
        for (int mt = 0; mt < 4; ++mt)
            af[mt] = *(const short8*)&Ab[(wr * 64 + mt * 16 + qm) * 32 + quad * 8];
#pragma unroll
        for (int nt = 0; nt < 4; ++nt)
            bf[nt] = *(const short8*)&Bb[(wc * 64 + nt * 16 + qm) * 32 + quad * 8];
#pragma unroll
        for (int mt = 0; mt < 4; ++mt)
#pragma unroll
            for (int nt = 0; nt < 4; ++nt)
                acc[mt][nt] = __builtin_amdgcn_mfma_f32_16x16x32_bf16(af[mt], bf[nt], acc[mt][nt], 0, 0, 0);
        __syncthreads();
    }

    const int whichB = n0 >> 8;   // bx 0,1 -> q; 2,3 -> k; 4,5 -> v
#pragma unroll
    for (int mt = 0; mt < 4; ++mt) {
#pragma unroll
        for (int r = 0; r < 4; ++r) {
            int m = m0 + wr * 64 + mt * 16 + quad * 4 + r;
            int b = (m >= NPOS) ? 1 : 0;
            int pos = m - b * NPOS;
            float c0 = 0.f, s0 = 0.f, c1 = 0.f, s1 = 0.f;
            if (whichB < 2) {
                float posf = (float)pos;
                __sincosf(posf * INVF[qm >> 1], &s0, &c0);
                __sincosf(posf * INVF[8 + (qm >> 1)], &s1, &c1);
            }
#pragma unroll
            for (int nt = 0; nt < 4; ++nt) {
                int c = n0 + wc * 64 + nt * 16 + qm;
                int head = (c >> 5) & 7;
                int d = (nt & 1) * 16 + qm;
                float val = acc[mt][nt][r];
                if (whichB < 2) {
                    float other = __shfl_xor(val, 1);   // d parity == lane parity
                    float cf = (nt & 1) ? c1 : c0, sf = (nt & 1) ? s1 : s0;
                    val = (lane & 1) ? (val * cf + other * sf)
                                     : (val * cf - other * sf);
                }
                if (whichB == 0) {
                    qb[(size_t)m * 256 + head * 32 + d] = f2h(val * QSCALE);
                } else {
                    ushort* dst = (whichB == 1) ? kws : vws;
                    dst[(size_t)(((b << 3) + head) * NPOS + pos) * 32 + d] = f2h(val);
                }
            }
        }
    }
}

// Neighborhood attention: f16 q/k/v, single-pass softmax (no max-sub; |s|<~1),
// scores via v_dot2_f32_f16 when available. Output bf16 -> ab.
__global__ __launch_bounds__(256) void nattn(
    const ushort* __restrict__ kws, const ushort* __restrict__ vws,
    const ushort* __restrict__ qb, ushort* __restrict__ ab)
{
    __shared__ ushort Ksm[196 * 32];
    __shared__ ushort Vsm[196 * 32];
    const int t = threadIdx.x;
    const int bh = blockIdx.y;
    const int b = bh >> 3, head = bh & 7;
    const int ti = blockIdx.x / 7, tj = blockIdx.x % 7;
    const int ty0 = ti * 8, tx0 = tj * 8;
    const int r0 = min(max(ty0 - 3, 0), HH - 14);
    const int c0 = min(max(tx0 - 3, 0), WW - 14);
    const ushort* kbase = kws + (size_t)bh * NPOS * 32;
    const ushort* vbase = vws + (size_t)bh * NPOS * 32;

    for (int idx = t; idx < 196 * 4; idx += 256) {
        int p = idx >> 2, ch = idx & 3;
        int g = ((r0 + p / 14) * WW + (c0 + p % 14)) * 32 + ch * 8;
        *(uint4*)&Ksm[p * 32 + ch * 8] = *(const uint4*)&kbase[g];
        *(uint4*)&Vsm[p * 32 + ch * 8] = *(const uint4*)&vbase[g];
    }
    __syncthreads();

    const int lane = t & 63, wv = t >> 6;
    const int qsub = lane & 15, part = lane >> 4;
    const int qi = wv * 16 + qsub;
    const int qy = ty0 + (qi >> 3), qx = tx0 + (qi & 7);
    const int pos = qy * WW + qx;
    const size_t qoff = (size_t)(b * NPOS + pos) * 256 + head * 32;

    half2v qp[16];
    {
        const uint* q4 = (const uint*)(qb + qoff);
#pragma unroll
        for (int c2 = 0; c2 < 16; ++c2) qp[c2] = u2h2(q4[c2]);
    }

    const int rs = min(max(qy - 3, 0), HH - 7) - r0;
    const int cs = min(max(qx - 3, 0), WW - 7) - c0;

    float sum = 0.f;
    float facc[32];
#pragma unroll
    for (int c = 0; c < 32; ++c) facc[c] = 0.f;

#pragma unroll
    for (int j = 0; j < 13; ++j) {
        int kk = part + 4 * j;
        if (kk < 49) {
            int kp = (rs + kk / 7) * 14 + (cs + kk % 7);
            const uint4* Kp = (const uint4*)&Ksm[kp * 32];
            float s = 0.f;
#pragma unroll
            for (int c8 = 0; c8 < 4; ++c8) {
                uint4 u = Kp[c8];
#if __has_builtin(__builtin_amdgcn_fdot2)
                s = __builtin_amdgcn_fdot2(u2h2(u.x), qp[4 * c8 + 0], s, false);
                s = __builtin_amdgcn_fdot2(u2h2(u.y), qp[4 * c8 + 1], s, false);
                s = __builtin_amdgcn_fdot2(u2h2(u.z), qp[4 * c8 + 2], s, false);
                s = __builtin_amdgcn_fdot2(u2h2(u.w), qp[4 * c8 + 3], s, false);
#else
                half2v k0h = u2h2(u.x), k1h = u2h2(u.y), k2h = u2h2(u.z), k3h = u2h2(u.w);
                half2v q0 = qp[4 * c8 + 0], q1 = qp[4 * c8 + 1];
                half2v q2 = qp[4 * c8 + 2], q3 = qp[4 * c8 + 3];
                s += (float)k0h[0] * (float)q0[0] + (float)k0h[1] * (float)q0[1];
                s += (float)k1h[0] * (float)q1[0] + (float)k1h[1] * (float)q1[1];
                s += (float)k2h[0] * (float)q2[0] + (float)k2h[1] * (float)q2[1];
                s += (float)k3h[0] * (float)q3[0] + (float)k3h[1] * (float)q3[1];
#endif
            }
            float e = __expf(s);           // scale folded into q; |s| small
            sum += e;
            const uint4* Vp = (const uint4*)&Vsm[kp * 32];
#pragma unroll
            for (int c8 = 0; c8 < 4; ++c8) {
                uint4 u = Vp[c8];
                float* fv = facc + 8 * c8;
                half2v h0 = u2h2(u.x), h1 = u2h2(u.y), h2 = u2h2(u.z), h3 = u2h2(u.w);
                fv[0] += e * (float)h0[0]; fv[1] += e * (float)h0[1];
                fv[2] += e * (float)h1[0]; fv[3] += e * (float)h1[1];
                fv[4] += e * (float)h2[0]; fv[5] += e * (float)h2[1];
                fv[6] += e * (float)h3[0]; fv[7] += e * (float)h3[1];
            }
        }
    }
    sum += __shfl_xor(sum, 16);
    sum += __shfl_xor(sum, 32);
#pragma unroll
    for (int c = 0; c < 32; ++c) {
        facc[c] += __shfl_xor(facc[c], 16);
        facc[c] += __shfl_xor(facc[c], 32);
    }

    if (part == 0) {
        float inv = 1.f / sum;
        uint* op = (uint*)(ab + qoff);
#pragma unroll
        for (int c2 = 0; c2 < 16; ++c2) {
            uint lo = f2b(facc[2 * c2] * inv);
            uint hi = f2b(facc[2 * c2 + 1] * inv);
            op[c2] = lo | (hi << 16);
        }
    }
}

// Projection 64x64 tiles; A (attn bf16) and B (wprojT) via async16. fp32 out.
__global__ __launch_bounds__(256) void proj_fast(
    const ushort* __restrict__ ab, const ushort* __restrict__ wprojT,
    const float* __restrict__ bias, float* __restrict__ out)
{
    __shared__ ushort Ap[64 * 32];
    __shared__ ushort Bp[64 * 32];
    const int t = threadIdx.x;
    const int lane = t & 63, wv = t >> 6;
    const int qm = lane & 15, quad = lane >> 4;
    const int n0 = blockIdx.x * 64, m0 = blockIdx.y * 64;
    const int wr = wv >> 1, wc = wv & 1;
    const int srow = lane >> 2, scol = (lane & 3) * 8;

    floatx4 acc[2][2];
#pragma unroll
    for (int i = 0; i < 2; ++i)
#pragma unroll
        for (int j = 0; j < 2; ++j) acc[i][j] = (floatx4){0.f, 0.f, 0.f, 0.f};

    for (int k0 = 0; k0 < 256; k0 += 32) {
        int rbase = wv * 16;
        async16(&ab[(size_t)(m0 + rbase + srow) * 256 + k0 + scol], &Ap[rbase * 32]);
        async16(&wprojT[(size_t)(n0 + rbase + srow) * 256 + k0 + scol], &Bp[rbase * 32]);
        __syncthreads();
        short8 af[2], bf[2];
#pragma unroll
        for (int mt = 0; mt < 2; ++mt)
            af[mt] = *(const short8*)&Ap[(wr * 32 + mt * 16 + qm) * 32 + quad * 8];
#pragma unroll
        for (int nt = 0; nt < 2; ++nt)
            bf[nt] = *(const short8*)&Bp[(wc * 32 + nt * 16 + qm) * 32 + quad * 8];
#pragma unroll
        for (int mt = 0; mt < 2; ++mt)
#pragma unroll
            for (int nt = 0; nt < 2; ++nt)
                acc[mt][nt] = __builtin_amdgcn_mfma_f32_16x16x32_bf16(af[mt], bf[nt], acc[mt][nt], 0, 0, 0);
        __syncthreads();
    }

#pragma unroll
    for (int nt = 0; nt < 2; ++nt) {
        int c = n0 + wc * 32 + nt * 16 + qm;
        float bv = bias[c];
#pragma unroll
        for (int mt = 0; mt < 2; ++mt) {
#pragma unroll
            for (int r = 0; r < 4; ++r) {
                int m = m0 + wr * 32 + mt * 16 + quad * 4 + r;
                out[(size_t)m * 256 + c] = acc[mt][nt][r] + bv;
            }
        }
    }
}

// ===========================================================================
// FALLBACK PATH (r8 kernels, verified; used only if ws too small)
// ===========================================================================
__global__ __launch_bounds__(256) void qkv_fb(
    const float* __restrict__ x, const float* __restrict__ w,
    float* __restrict__ qa, ushort* __restrict__ kws, ushort* __restrict__ vws)
{
    __shared__ ushort Asm[64 * 40];
    __shared__ ushort Bsm[64 * 40];
    const int t = threadIdx.x;
    const int m0 = blockIdx.y * 64;
    const int n0 = blockIdx.x * 64;
    const int lane = t & 63, wv = t >> 6;
    const int qm = lane & 15, quad = lane >> 4;

    floatx4 acc[4];
#pragma unroll
    for (int i = 0; i < 4; ++i) acc[i] = (floatx4){0.f, 0.f, 0.f, 0.f};

    for (int k0 = 0; k0 < 256; k0 += 32) {
#pragma unroll
        for (int i = 0; i < 2; ++i) {
            int p = t + 256 * i;
            int row = p >> 3, f4 = p & 7;
            float4 v = *(const float4*)&x[(size_t)(m0 + row) * 256 + k0 + f4 * 4];
            ushort4 h;
            h.x = f2b(v.x); h.y = f2b(v.y); h.z = f2b(v.z); h.w = f2b(v.w);
            *(ushort4*)&Asm[row * 40 + f4 * 4] = h;
        }
#pragma unroll
        for (int i = 0; i < 8; ++i) {
            int e = t + 256 * i;
            int kk = e >> 6, nn = e & 63;
            Bsm[nn * 40 + kk] = f2b(w[(size_t)(k0 + kk) * 768 + n0 + nn]);
        }
        __syncthreads();
        short8 af = *(const short8*)&Asm[(wv * 16 + qm) * 40 + quad * 8];
#pragma unroll
        for (int nt = 0; nt < 4; ++nt) {
            short8 bf = *(const short8*)&Bsm[(nt * 16 + qm) * 40 + quad * 8];
            acc[nt] = __builtin_amdgcn_mfma_f32_16x16x32_bf16(af, bf, acc[nt], 0, 0, 0);
        }
        __syncthreads();
    }

    const int whichB = n0 >> 8;
#pragma unroll
    for (int r = 0; r < 4; ++r) {
        int m = m0 + wv * 16 + quad * 4 + r;
        int b = (m >= NPOS) ? 1 : 0;
        int pos = m - b * NPOS;
        float cf[2], sf[2];
        if (whichB < 2) {
            float posf = (float)pos;
            __sincosf(posf * INVF[qm >> 1], &sf[0], &cf[0]);
            __sincosf(posf * INVF[8 + (qm >> 1)], &sf[1], &cf[1]);
        }
#pragma unroll
        for (int nt = 0; nt < 4; ++nt) {
            int par = nt & 1;
            int d = par * 16 + qm;
            int head = ((n0 >> 5) & 7) + (nt >> 1);
            float val = acc[nt][r];
            if (whichB < 2) {
                float other = __shfl_xor(val, 1);
                val = (lane & 1) ? (val * cf[par] + other * sf[par])
                                 : (val * cf[par] - other * sf[par]);
            }
            if (whichB == 0) {
                qa[(size_t)m * 256 + head * 32 + d] = val;
            } else {
                ushort* dst = (whichB == 1) ? kws : vws;
                dst[(size_t)(((b << 3) + head) * NPOS + pos) * 32 + d] = f2b(val);
            }
        }
    }
}

__global__ __launch_bounds__(256) void nattn_fb(
    const ushort* __restrict__ kws, const ushort* __restrict__ vws, float* qa)
{
    __shared__ ushort Ksm[196 * 32];
    __shared__ ushort Vsm[196 * 32];
    const int t = threadIdx.x;
    const int bh = blockIdx.y;
    const int b = bh >> 3, head = bh & 7;
    const int ti = blockIdx.x / 7, tj = blockIdx.x % 7;
    const int ty0 = ti * 8, tx0 = tj * 8;
    const int r0 = min(max(ty0 - 3, 0), HH - 14);
    const int c0 = min(max(tx0 - 3, 0), WW - 14);
    const ushort* kbase = kws + (size_t)bh * NPOS * 32;
    const ushort* vbase = vws + (size_t)bh * NPOS * 32;

    for (int idx = t; idx < 196 * 4; idx += 256) {
        int p = idx >> 2, ch = idx & 3;
        int g = ((r0 + p / 14) * WW + (c0 + p % 14)) * 32 + ch * 8;
        *(uint4*)&Ksm[p * 32 + ch * 8] = *(const uint4*)&kbase[g];
        *(uint4*)&Vsm[p * 32 + ch * 8] = *(const uint4*)&vbase[g];
    }
    __syncthreads();

    const int lane = t & 63, wv = t >> 6;
    const int qsub = lane & 15, part = lane >> 4;
    const int qi = wv * 16 + qsub;
    const int qy = ty0 + (qi >> 3), qx = tx0 + (qi & 7);
    const int pos = qy * WW + qx;
    float* qptr = qa + (size_t)(b * NPOS + pos) * 256 + head * 32;

    float qf[32];
#pragma unroll
    for (int c4 = 0; c4 < 8; ++c4) {
        float4 v = *(const float4*)&qptr[c4 * 4];
        qf[4 * c4] = v.x; qf[4 * c4 + 1] = v.y; qf[4 * c4 + 2] = v.z; qf[4 * c4 + 3] = v.w;
    }

    const int rs = min(max(qy - 3, 0), HH - 7) - r0;
    const int cs = min(max(qx - 3, 0), WW - 7) - c0;

    float sum = 0.f;
    float facc[32];
#pragma unroll
    for (int c = 0; c < 32; ++c) facc[c] = 0.f;
#pragma unroll
    for (int j = 0; j < 13; ++j) {
        int kk = part + 4 * j;
        if (kk < 49) {
            int kp = (rs + kk / 7) * 14 + (cs + kk % 7);
            const uint4* Kp = (const uint4*)&Ksm[kp * 32];
            float s = 0.f;
#pragma unroll
            for (int c8 = 0; c8 < 4; ++c8) {
                uint4 u = Kp[c8];
                const float* qv = qf + 8 * c8;
                s += qv[0] * b2f((ushort)u.x) + qv[1] * b2f((ushort)(u.x >> 16));
                s += qv[2] * b2f((ushort)u.y) + qv[3] * b2f((ushort)(u.y >> 16));
                s += qv[4] * b2f((ushort)u.z) + qv[5] * b2f((ushort)(u.z >> 16));
                s += qv[6] * b2f((ushort)u.w) + qv[7] * b2f((ushort)(u.w >> 16));
            }
            float e = __expf(s * 0.17677669529663687f);
            sum += e;
            const uint4* Vp = (const uint4*)&Vsm[kp * 32];
#pragma unroll
            for (int c8 = 0; c8 < 4; ++c8) {
                uint4 u = Vp[c8];
                float* fv = facc + 8 * c8;
                fv[0] += e * b2f((ushort)u.x); fv[1] += e * b2f((ushort)(u.x >> 16));
                fv[2] += e * b2f((ushort)u.y); fv[3] += e * b2f((ushort)(u.y >> 16));
                fv[4] += e * b2f((ushort)u.z); fv[5] += e * b2f((ushort)(u.z >> 16));
                fv[6] += e * b2f((ushort)u.w); fv[7] += e * b2f((ushort)(u.w >> 16));
            }
        }
    }
    sum += __shfl_xor(sum, 16);
    sum += __shfl_xor(sum, 32);
#pragma unroll
    for (int c = 0; c < 32; ++c) {
        facc[c] += __shfl_xor(facc[c], 16);
        facc[c] += __shfl_xor(facc[c], 32);
    }

    if (part == 0) {
        float inv = 1.f / sum;
#pragma unroll
        for (int c4 = 0; c4 < 8; ++c4) {
            float4 o;
            o.x = facc[4 * c4] * inv; o.y = facc[4 * c4 + 1] * inv;
            o.z = facc[4 * c4 + 2] * inv; o.w = facc[4 * c4 + 3] * inv;
            *(float4*)&qptr[c4 * 4] = o;
        }
    }
}

__global__ __launch_bounds__(256) void proj_fb(
    const float* __restrict__ w, const float* __restrict__ bias, float* out)
{
    __shared__ ushort Apad[64 * 264];
    __shared__ ushort Bsm[256 * 40];
    const int t = threadIdx.x;
    const int m0 = blockIdx.x * 64;
    const int lane = t & 63, wv = t >> 6;
    const int qm = lane & 15, quad = lane >> 4;

    {
        int row = t >> 2, cb = (t & 3) * 64;
        const float4* src = (const float4*)&out[(size_t)(m0 + row) * 256 + cb];
#pragma unroll
        for (int i = 0; i < 16; ++i) {
            float4 v = src[i];
            ushort4 h;
            h.x = f2b(v.x); h.y = f2b(v.y); h.z = f2b(v.z); h.w = f2b(v.w);
            *(ushort4*)&Apad[row * 264 + cb + i * 4] = h;
        }
    }

    floatx4 acc[4][4];
#pragma unroll
    for (int i = 0; i < 4; ++i)
#pragma unroll
        for (int j = 0; j < 4; ++j) acc[i][j] = (floatx4){0.f, 0.f, 0.f, 0.f};

    __syncthreads();

    for (int k0 = 0; k0 < 256; k0 += 32) {
#pragma unroll
        for (int i = 0; i < 32; ++i) {
            int e = t + 256 * i;
            int kk = e >> 8, nn = e & 255;
            Bsm[nn * 40 + kk] = f2b(w[(size_t)(k0 + kk) * 256 + nn]);
        }
        __syncthreads();
        short8 af[4];
#pragma unroll
        for (int mt = 0; mt < 4; ++mt)
            af[mt] = *(const short8*)&Apad[(mt * 16 + qm) * 264 + k0 + quad * 8];
#pragma unroll
        for (int nt = 0; nt < 4; ++nt) {
            short8 bf = *(const short8*)&Bsm[(wv * 64 + nt * 16 + qm) * 40 + quad * 8];
#pragma unroll
            for (int mt = 0; mt < 4; ++mt)
                acc[mt][nt] = __builtin_amdgcn_mfma_f32_16x16x32_bf16(af[mt], bf, acc[mt][nt], 0, 0, 0);
        }
        __syncthreads();
    }

#pragma unroll
    for (int nt = 0; nt < 4; ++nt) {
        int c = wv * 64 + nt * 16 + qm;
        float bv = bias[c];
#pragma unroll
        for (int mt = 0; mt < 4; ++mt) {
#pragma unroll
            for (int r = 0; r < 4; ++r) {
                int m = m0 + mt * 16 + quad * 4 + r;
                out[(size_t)m * 256 + c] = acc[mt][nt][r] + bv;
            }
        }
    }
}

// ===========================================================================
extern "C" void kernel_launch(void* const* d_in, const int* in_sizes, int n_in,
                              void* d_out, int out_size, void* d_ws, size_t ws_size,
                              hipStream_t stream)
{
    const float* x     = (const float*)d_in[0];
    const float* wqkv  = (const float*)d_in[1];
    const float* wproj = (const float*)d_in[2];
    const float* bproj = (const float*)d_in[3];
    float* out = (float*)d_out;
    char* ws = (char*)d_ws;

    // fast-path ws layout (bytes):
    //   wqkvT   393,216 @ 0
    //   wprojT  131,072 @   393,216
    //   qb    3,211,264 @   524,288   (f16, scale folded)
    //   kws   3,211,264 @ 3,735,552   (f16)
    //   vws   3,211,264 @ 6,946,816   (f16)
    //   ab    3,211,264 @ 10,158,080  (bf16) -> total 13,369,344
    if (ws_size >= 13369344ull) {
        ushort* wqkvT  = (ushort*)(ws);
        ushort* wprojT = (ushort*)(ws + 393216);
        ushort* qb     = (ushort*)(ws + 524288);
        ushort* kws    = (ushort*)(ws + 3735552);
        ushort* vws    = (ushort*)(ws + 6946816);
        ushort* ab     = (ushort*)(ws + 10158080);

        hipLaunchKernelGGL(prep, dim3(64), dim3(256), 0, stream,
                           wqkv, wproj, wqkvT, wprojT);
        hipLaunchKernelGGL(qkv_fast, dim3(6, 49), dim3(256), 0, stream,
                           x, wqkvT, qb, kws, vws);
        hipLaunchKernelGGL(nattn, dim3(49, BATCH * HEADS), dim3(256), 0, stream,
                           kws, vws, qb, ab);
        hipLaunchKernelGGL(proj_fast, dim3(4, 98), dim3(256), 0, stream,
                           ab, wprojT, bproj, out);
    } else {
        ushort* kws = (ushort*)ws;
        ushort* vws = (ushort*)(ws + 3211264);
        hipLaunchKernelGGL(qkv_fb, dim3(12, 98), dim3(256), 0, stream,
                           x, wqkv, out, kws, vws);
        hipLaunchKernelGGL(nattn_fb, dim3(49, BATCH * HEADS), dim3(256), 0, stream,
                           kws, vws, out);
        hipLaunchKernelGGL(proj_fb, dim3(98), dim3(256), 0, stream,
                           wproj, bproj, out);
    }
}

// Round 12
// 111.421 us; speedup vs baseline: 1.2926x; 1.0346x over previous
//
#include <hip/hip_runtime.h>
#include <hip/hip_bf16.h>

#define HH 56
#define WW 56
#define NPOS 3136
#define BATCH 2
#define HEADS 8

typedef __attribute__((ext_vector_type(4))) float floatx4;
typedef __attribute__((ext_vector_type(8))) short short8;
typedef __attribute__((ext_vector_type(2))) _Float16 half2v;

static __device__ __forceinline__ ushort f2b(float f) {
    __hip_bfloat16 h = __float2bfloat16(f);
    return *reinterpret_cast<ushort*>(&h);
}
static __device__ __forceinline__ float b2f(ushort u) {
    return __uint_as_float(((uint)u) << 16);
}
static __device__ __forceinline__ ushort f2h(float f) {
    union { _Float16 h; ushort u; } c; c.h = (_Float16)f; return c.u;
}
static __device__ __forceinline__ half2v u2h2(uint u) {
    union { uint u; half2v h; } c; c.u = u; return c.h;
}

// async global->LDS, 16B per lane. LDS dest = wave-uniform base + lane*16.
static __device__ __forceinline__ void async16(const ushort* g, ushort* l) {
    __builtin_amdgcn_global_load_lds(
        (const __attribute__((address_space(1))) unsigned int*)g,
        (__attribute__((address_space(3))) unsigned int*)l, 16, 0, 0);
}

// fl32(10^(-j/4)) == np.float32 inv-freq table
__constant__ float INVF[16] = {
    1.0f,   0.5623413251903491f,   0.31622776601683794f,   0.17782794100389228f,
    0.1f,   0.05623413251903491f,  0.031622776601683794f,  0.017782794100389228f,
    0.01f,  0.005623413251903491f, 0.0031622776601683794f, 0.0017782794100389228f,
    0.001f, 0.0005623413251903491f,0.00031622776601683794f,0.00017782794100389228f
};

#define QSCALE 0.17677669529663687f   // 32^-0.5, folded into q at store

// ===========================================================================
// FAST PATH
// ===========================================================================

// Prepass: xb cvt (98) + wqkvT (48) + wprojT (16) = 162 blocks.
__global__ __launch_bounds__(256) void prep(
    const float* __restrict__ x,
    const float* __restrict__ wqkv, const float* __restrict__ wproj,
    ushort* __restrict__ xb, ushort* __restrict__ wqkvT,
    ushort* __restrict__ wprojT)
{
    __shared__ ushort Ls[64 * 65];
    const int bid = blockIdx.x, t = threadIdx.x;
    if (bid < 98) {                         // x fp32 -> bf16 (64 rows/block)
#pragma unroll
        for (int i = 0; i < 16; ++i) {
            int idx4 = bid * 4096 + i * 256 + t;      // float4 index
            float4 v = *(const float4*)&x[(size_t)idx4 * 4];
            ushort4 h; h.x = f2b(v.x); h.y = f2b(v.y); h.z = f2b(v.z); h.w = f2b(v.w);
            *(ushort4*)&xb[(size_t)idx4 * 4] = h;
        }
    } else if (bid < 146) {                 // wqkv (256,768) -> wqkvT (768,256)
        int l = bid - 98;
        int nb = (l % 12) * 64, kb = (l / 12) * 64;
#pragma unroll
        for (int i = 0; i < 16; ++i) {
            int e = t + 256 * i, kk = e >> 6, nn = e & 63;
            Ls[kk * 65 + nn] = f2b(wqkv[(size_t)(kb + kk) * 768 + nb + nn]);
        }
        __syncthreads();
#pragma unroll
        for (int i = 0; i < 16; ++i) {
            int e = t + 256 * i, nn = e >> 6, kk = e & 63;
            wqkvT[(size_t)(nb + nn) * 256 + kb + kk] = Ls[kk * 65 + nn];
        }
    } else {                                // wproj (256,256) -> wprojT
        int l = bid - 146;
        int nb = (l & 3) * 64, kb = (l >> 2) * 64;
#pragma unroll
        for (int i = 0; i < 16; ++i) {
            int e = t + 256 * i, kk = e >> 6, nn = e & 63;
            Ls[kk * 65 + nn] = f2b(wproj[(size_t)(kb + kk) * 256 + nb + nn]);
        }
        __syncthreads();
#pragma unroll
        for (int i = 0; i < 16; ++i) {
            int e = t + 256 * i, nn = e >> 6, kk = e & 63;
            wprojT[(size_t)(nb + nn) * 256 + kb + kk] = Ls[kk * 65 + nn];
        }
    }
}

// QKV GEMM 128x128 tile. A and B both via global_load_lds (bf16 sources).
// Inline __sincosf RoPE. q (scaled) / k / v stored F16 -> ws. grid (6, 49).
__global__ __launch_bounds__(256) void qkv_fast(
    const ushort* __restrict__ xb, const ushort* __restrict__ wqkvT,
    ushort* __restrict__ qb, ushort* __restrict__ kws, ushort* __restrict__ vws)
{
    __shared__ ushort Ab[128 * 32];
    __shared__ ushort Bb[128 * 32];
    const int t = threadIdx.x;
    const int lane = t & 63, wv = t >> 6;
    const int qm = lane & 15, quad = lane >> 4;
    const int m0 = blockIdx.y * 128, n0 = blockIdx.x * 128;
    const int wr = wv >> 1, wc = wv & 1;
    const int srow = lane >> 2, scol = (lane & 3) * 8;

    floatx4 acc[4][4];
#pragma unroll
    for (int i = 0; i < 4; ++i)
#pragma unroll
        for (int j = 0; j < 4; ++j) acc[i][j] = (floatx4){0.f, 0.f, 0.f, 0.f};

    for (int k0 = 0; k0 < 256; k0 += 32) {
#pragma unroll
        for (int j = 0; j < 2; ++j) {
            int rbase = wv * 32 + j * 16;
            async16(&xb[(size_t)(m0 + rbase + srow) * 256 + k0 + scol], &Ab[rbase * 32]);
            async16(&wqkvT[(size_t)(n0 + rbase + srow) * 256 + k0 + scol], &Bb[rbase * 32]);
        }
        __syncthreads();
        short8 af[4], bf[4];
#pragma unroll
        for (int mt = 0; mt < 4; ++mt)
            af[mt] = *(const short8*)&Ab[(wr * 64 + mt * 16 + qm) * 32 + quad * 8];
#pragma unroll
        for (int nt = 0; nt < 4; ++nt)
            bf[nt] = *(const short8*)&Bb[(wc * 64 + nt * 16 + qm) * 32 + quad * 8];
#pragma unroll
        for (int mt = 0; mt < 4; ++mt)
#pragma unroll
            for (int nt = 0; nt < 4; ++nt)
                acc[mt][nt] = __builtin_amdgcn_mfma_f32_16x16x32_bf16(af[mt], bf[nt], acc[mt][nt], 0, 0, 0);
        __syncthreads();
    }

    const int whichB = n0 >> 8;   // bx 0,1 -> q; 2,3 -> k; 4,5 -> v
#pragma unroll
    for (int mt = 0; mt < 4; ++mt) {
#pragma unroll
        for (int r = 0; r < 4; ++r) {
            int m = m0 + wr * 64 + mt * 16 + quad * 4 + r;
            int b = (m >= NPOS) ? 1 : 0;
            int pos = m - b * NPOS;
            float c0 = 0.f, s0 = 0.f, c1 = 0.f, s1 = 0.f;
            if (whichB < 2) {
                float posf = (float)pos;
                __sincosf(posf * INVF[qm >> 1], &s0, &c0);
                __sincosf(posf * INVF[8 + (qm >> 1)], &s1, &c1);
            }
#pragma unroll
            for (int nt = 0; nt < 4; ++nt) {
                int c = n0 + wc * 64 + nt * 16 + qm;
                int head = (c >> 5) & 7;
                int d = (nt & 1) * 16 + qm;
                float val = acc[mt][nt][r];
                if (whichB < 2) {
                    float other = __shfl_xor(val, 1);   // d parity == lane parity
                    float cf = (nt & 1) ? c1 : c0, sf = (nt & 1) ? s1 : s0;
                    val = (lane & 1) ? (val * cf + other * sf)
                                     : (val * cf - other * sf);
                }
                if (whichB == 0) {
                    qb[(size_t)m * 256 + head * 32 + d] = f2h(val * QSCALE);
                } else {
                    ushort* dst = (whichB == 1) ? kws : vws;
                    dst[(size_t)(((b << 3) + head) * NPOS + pos) * 32 + d] = f2h(val);
                }
            }
        }
    }
}

// Neighborhood attention: f16 q/k/v, single-pass softmax, v_dot2 scores,
// packed v_pk_fma_f16 V-accumulate. Output bf16 -> ab.
__global__ __launch_bounds__(256) void nattn(
    const ushort* __restrict__ kws, const ushort* __restrict__ vws,
    const ushort* __restrict__ qb, ushort* __restrict__ ab)
{
    __shared__ ushort Ksm[196 * 32];
    __shared__ ushort Vsm[196 * 32];
    const int t = threadIdx.x;
    const int bh = blockIdx.y;
    const int b = bh >> 3, head = bh & 7;
    const int ti = blockIdx.x / 7, tj = blockIdx.x % 7;
    const int ty0 = ti * 8, tx0 = tj * 8;
    const int r0 = min(max(ty0 - 3, 0), HH - 14);
    const int c0 = min(max(tx0 - 3, 0), WW - 14);
    const ushort* kbase = kws + (size_t)bh * NPOS * 32;
    const ushort* vbase = vws + (size_t)bh * NPOS * 32;

    for (int idx = t; idx < 196 * 4; idx += 256) {
        int p = idx >> 2, ch = idx & 3;
        int g = ((r0 + p / 14) * WW + (c0 + p % 14)) * 32 + ch * 8;
        *(uint4*)&Ksm[p * 32 + ch * 8] = *(const uint4*)&kbase[g];
        *(uint4*)&Vsm[p * 32 + ch * 8] = *(const uint4*)&vbase[g];
    }
    __syncthreads();

    const int lane = t & 63, wv = t >> 6;
    const int qsub = lane & 15, part = lane >> 4;
    const int qi = wv * 16 + qsub;
    const int qy = ty0 + (qi >> 3), qx = tx0 + (qi & 7);
    const int pos = qy * WW + qx;
    const size_t qoff = (size_t)(b * NPOS + pos) * 256 + head * 32;

    half2v qp[16];
    {
        const uint* q4 = (const uint*)(qb + qoff);
#pragma unroll
        for (int c2 = 0; c2 < 16; ++c2) qp[c2] = u2h2(q4[c2]);
    }

    const int rs = min(max(qy - 3, 0), HH - 7) - r0;
    const int cs = min(max(qx - 3, 0), WW - 7) - c0;

    float sum = 0.f;
    half2v vacc[16];
#pragma unroll
    for (int c = 0; c < 16; ++c) vacc[c] = (half2v){(_Float16)0.f, (_Float16)0.f};

#pragma unroll
    for (int j = 0; j < 13; ++j) {
        int kk = part + 4 * j;
        if (kk < 49) {
            int kp = (rs + kk / 7) * 14 + (cs + kk % 7);
            const uint4* Kp = (const uint4*)&Ksm[kp * 32];
            float s = 0.f;
#pragma unroll
            for (int c8 = 0; c8 < 4; ++c8) {
                uint4 u = Kp[c8];
#if __has_builtin(__builtin_amdgcn_fdot2)
                s = __builtin_amdgcn_fdot2(u2h2(u.x), qp[4 * c8 + 0], s, false);
                s = __builtin_amdgcn_fdot2(u2h2(u.y), qp[4 * c8 + 1], s, false);
                s = __builtin_amdgcn_fdot2(u2h2(u.z), qp[4 * c8 + 2], s, false);
                s = __builtin_amdgcn_fdot2(u2h2(u.w), qp[4 * c8 + 3], s, false);
#else
                half2v k0h = u2h2(u.x), k1h = u2h2(u.y), k2h = u2h2(u.z), k3h = u2h2(u.w);
                half2v q0 = qp[4 * c8 + 0], q1 = qp[4 * c8 + 1];
                half2v q2 = qp[4 * c8 + 2], q3 = qp[4 * c8 + 3];
                s += (float)k0h[0] * (float)q0[0] + (float)k0h[1] * (float)q0[1];
                s += (float)k1h[0] * (float)q1[0] + (float)k1h[1] * (float)q1[1];
                s += (float)k2h[0] * (float)q2[0] + (float)k2h[1] * (float)q2[1];
                s += (float)k3h[0] * (float)q3[0] + (float)k3h[1] * (float)q3[1];
#endif
            }
            float e = __expf(s);           // scale folded into q; |s| small
            sum += e;
            _Float16 eh = (_Float16)e;
            half2v e2 = (half2v){eh, eh};
            const uint4* Vp = (const uint4*)&Vsm[kp * 32];
#pragma unroll
            for (int c8 = 0; c8 < 4; ++c8) {
                uint4 u = Vp[c8];
                vacc[4 * c8 + 0] += e2 * u2h2(u.x);
                vacc[4 * c8 + 1] += e2 * u2h2(u.y);
                vacc[4 * c8 + 2] += e2 * u2h2(u.z);
                vacc[4 * c8 + 3] += e2 * u2h2(u.w);
            }
        }
    }
    sum += __shfl_xor(sum, 16);
    sum += __shfl_xor(sum, 32);

    float facc[32];
#pragma unroll
    for (int c2 = 0; c2 < 16; ++c2) {
        facc[2 * c2]     = (float)vacc[c2][0];
        facc[2 * c2 + 1] = (float)vacc[c2][1];
    }
#pragma unroll
    for (int c = 0; c < 32; ++c) {
        facc[c] += __shfl_xor(facc[c], 16);
        facc[c] += __shfl_xor(facc[c], 32);
    }

    if (part == 0) {
        float inv = 1.f / sum;
        uint* op = (uint*)(ab + qoff);
#pragma unroll
        for (int c2 = 0; c2 < 16; ++c2) {
            uint lo = f2b(facc[2 * c2] * inv);
            uint hi = f2b(facc[2 * c2 + 1] * inv);
            op[c2] = lo | (hi << 16);
        }
    }
}

// Projection 64x64 tiles; A (attn bf16) and B (wprojT) via async16. fp32 out.
__global__ __launch_bounds__(256) void proj_fast(
    const ushort* __restrict__ ab, const ushort* __restrict__ wprojT,
    const float* __restrict__ bias, float* __restrict__ out)
{
    __shared__ ushort Ap[64 * 32];
    __shared__ ushort Bp[64 * 32];
    const int t = threadIdx.x;
    const int lane = t & 63, wv = t >> 6;
    const int qm = lane & 15, quad = lane >> 4;
    const int n0 = blockIdx.x * 64, m0 = blockIdx.y * 64;
    const int wr = wv >> 1, wc = wv & 1;
    const int srow = lane >> 2, scol = (lane & 3) * 8;

    floatx4 acc[2][2];
#pragma unroll
    for (int i = 0; i < 2; ++i)
#pragma unroll
        for (int j = 0; j < 2; ++j) acc[i][j] = (floatx4){0.f, 0.f, 0.f, 0.f};

    for (int k0 = 0; k0 < 256; k0 += 32) {
        int rbase = wv * 16;
        async16(&ab[(size_t)(m0 + rbase + srow) * 256 + k0 + scol], &Ap[rbase * 32]);
        async16(&wprojT[(size_t)(n0 + rbase + srow) * 256 + k0 + scol], &Bp[rbase * 32]);
        __syncthreads();
        short8 af[2], bf[2];
#pragma unroll
        for (int mt = 0; mt < 2; ++mt)
            af[mt] = *(const short8*)&Ap[(wr * 32 + mt * 16 + qm) * 32 + quad * 8];
#pragma unroll
        for (int nt = 0; nt < 2; ++nt)
            bf[nt] = *(const short8*)&Bp[(wc * 32 + nt * 16 + qm) * 32 + quad * 8];
#pragma unroll
        for (int mt = 0; mt < 2; ++mt)
#pragma unroll
            for (int nt = 0; nt < 2; ++nt)
                acc[mt][nt] = __builtin_amdgcn_mfma_f32_16x16x32_bf16(af[mt], bf[nt], acc[mt][nt], 0, 0, 0);
        __syncthreads();
    }

#pragma unroll
    for (int nt = 0; nt < 2; ++nt) {
        int c = n0 + wc * 32 + nt * 16 + qm;
        float bv = bias[c];
#pragma unroll
        for (int mt = 0; mt < 2; ++mt) {
#pragma unroll
            for (int r = 0; r < 4; ++r) {
                int m = m0 + wr * 32 + mt * 16 + quad * 4 + r;
                out[(size_t)m * 256 + c] = acc[mt][nt][r] + bv;
            }
        }
    }
}

// ===========================================================================
// FALLBACK PATH (r8 kernels, verified; used only if ws too small)
// ===========================================================================
__global__ __launch_bounds__(256) void qkv_fb(
    const float* __restrict__ x, const float* __restrict__ w,
    float* __restrict__ qa, ushort* __restrict__ kws, ushort* __restrict__ vws)
{
    __shared__ ushort Asm[64 * 40];
    __shared__ ushort Bsm[64 * 40];
    const int t = threadIdx.x;
    const int m0 = blockIdx.y * 64;
    const int n0 = blockIdx.x * 64;
    const int lane = t & 63, wv = t >> 6;
    const int qm = lane & 15, quad = lane >> 4;

    floatx4 acc[4];
#pragma unroll
    for (int i = 0; i < 4; ++i) acc[i] = (floatx4){0.f, 0.f, 0.f, 0.f};

    for (int k0 = 0; k0 < 256; k0 += 32) {
#pragma unroll
        for (int i = 0; i < 2; ++i) {
            int p = t + 256 * i;
            int row = p >> 3, f4 = p & 7;
            float4 v = *(const float4*)&x[(size_t)(m0 + row) * 256 + k0 + f4 * 4];
            ushort4 h;
            h.x = f2b(v.x); h.y = f2b(v.y); h.z = f2b(v.z); h.w = f2b(v.w);
            *(ushort4*)&Asm[row * 40 + f4 * 4] = h;
        }
#pragma unroll
        for (int i = 0; i < 8; ++i) {
            int e = t + 256 * i;
            int kk = e >> 6, nn = e & 63;
            Bsm[nn * 40 + kk] = f2b(w[(size_t)(k0 + kk) * 768 + n0 + nn]);
        }
        __syncthreads();
        short8 af = *(const short8*)&Asm[(wv * 16 + qm) * 40 + quad * 8];
#pragma unroll
        for (int nt = 0; nt < 4; ++nt) {
            short8 bf = *(const short8*)&Bsm[(nt * 16 + qm) * 40 + quad * 8];
            acc[nt] = __builtin_amdgcn_mfma_f32_16x16x32_bf16(af, bf, acc[nt], 0, 0, 0);
        }
        __syncthreads();
    }

    const int whichB = n0 >> 8;
#pragma unroll
    for (int r = 0; r < 4; ++r) {
        int m = m0 + wv * 16 + quad * 4 + r;
        int b = (m >= NPOS) ? 1 : 0;
        int pos = m - b * NPOS;
        float cf[2], sf[2];
        if (whichB < 2) {
            float posf = (float)pos;
            __sincosf(posf * INVF[qm >> 1], &sf[0], &cf[0]);
            __sincosf(posf * INVF[8 + (qm >> 1)], &sf[1], &cf[1]);
        }
#pragma unroll
        for (int nt = 0; nt < 4; ++nt) {
            int par = nt & 1;
            int d = par * 16 + qm;
            int head = ((n0 >> 5) & 7) + (nt >> 1);
            float val = acc[nt][r];
            if (whichB < 2) {
                float other = __shfl_xor(val, 1);
                val = (lane & 1) ? (val * cf[par] + other * sf[par])
                                 : (val * cf[par] - other * sf[par]);
            }
            if (whichB == 0) {
                qa[(size_t)m * 256 + head * 32 + d] = val;
            } else {
                ushort* dst = (whichB == 1) ? kws : vws;
                dst[(size_t)(((b << 3) + head) * NPOS + pos) * 32 + d] = f2b(val);
            }
        }
    }
}

__global__ __launch_bounds__(256) void nattn_fb(
    const ushort* __restrict__ kws, const ushort* __restrict__ vws, float* qa)
{
    __shared__ ushort Ksm[196 * 32];
    __shared__ ushort Vsm[196 * 32];
    const int t = threadIdx.x;
    const int bh = blockIdx.y;
    const int b = bh >> 3, head = bh & 7;
    const int ti = blockIdx.x / 7, tj = blockIdx.x % 7;
    const int ty0 = ti * 8, tx0 = tj * 8;
    const int r0 = min(max(ty0 - 3, 0), HH - 14);
    const int c0 = min(max(tx0 - 3, 0), WW - 14);
    const ushort* kbase = kws + (size_t)bh * NPOS * 32;
    const ushort* vbase = vws + (size_t)bh * NPOS * 32;

    for (int idx = t; idx < 196 * 4; idx += 256) {
        int p = idx >> 2, ch = idx & 3;
        int g = ((r0 + p / 14) * WW + (c0 + p % 14)) * 32 + ch * 8;
        *(uint4*)&Ksm[p * 32 + ch * 8] = *(const uint4*)&kbase[g];
        *(uint4*)&Vsm[p * 32 + ch * 8] = *(const uint4*)&vbase[g];
    }
    __syncthreads();

    const int lane = t & 63, wv = t >> 6;
    const int qsub = lane & 15, part = lane >> 4;
    const int qi = wv * 16 + qsub;
    const int qy = ty0 + (qi >> 3), qx = tx0 + (qi & 7);
    const int pos = qy * WW + qx;
    float* qptr = qa + (size_t)(b * NPOS + pos) * 256 + head * 32;

    float qf[32];
#pragma unroll
    for (int c4 = 0; c4 < 8; ++c4) {
        float4 v = *(const float4*)&qptr[c4 * 4];
        qf[4 * c4] = v.x; qf[4 * c4 + 1] = v.y; qf[4 * c4 + 2] = v.z; qf[4 * c4 + 3] = v.w;
    }

    const int rs = min(max(qy - 3, 0), HH - 7) - r0;
    const int cs = min(max(qx - 3, 0), WW - 7) - c0;

    float sum = 0.f;
    float facc[32];
#pragma unroll
    for (int c = 0; c < 32; ++c) facc[c] = 0.f;
#pragma unroll
    for (int j = 0; j < 13; ++j) {
        int kk = part + 4 * j;
        if (kk < 49) {
            int kp = (rs + kk / 7) * 14 + (cs + kk % 7);
            const uint4* Kp = (const uint4*)&Ksm[kp * 32];
            float s = 0.f;
#pragma unroll
            for (int c8 = 0; c8 < 4; ++c8) {
                uint4 u = Kp[c8];
                const float* qv = qf + 8 * c8;
                s += qv[0] * b2f((ushort)u.x) + qv[1] * b2f((ushort)(u.x >> 16));
                s += qv[2] * b2f((ushort)u.y) + qv[3] * b2f((ushort)(u.y >> 16));
                s += qv[4] * b2f((ushort)u.z) + qv[5] * b2f((ushort)(u.z >> 16));
                s += qv[6] * b2f((ushort)u.w) + qv[7] * b2f((ushort)(u.w >> 16));
            }
            float e = __expf(s * 0.17677669529663687f);
            sum += e;
            const uint4* Vp = (const uint4*)&Vsm[kp * 32];
#pragma unroll
            for (int c8 = 0; c8 < 4; ++c8) {
                uint4 u = Vp[c8];
                float* fv = facc + 8 * c8;
                fv[0] += e * b2f((ushort)u.x); fv[1] += e * b2f((ushort)(u.x >> 16));
                fv[2] += e * b2f((ushort)u.y); fv[3] += e * b2f((ushort)(u.y >> 16));
                fv[4] += e * b2f((ushort)u.z); fv[5] += e * b2f((ushort)(u.z >> 16));
                fv[6] += e * b2f((ushort)u.w); fv[7] += e * b2f((ushort)(u.w >> 16));
            }
        }
    }
    sum += __shfl_xor(sum, 16);
    sum += __shfl_xor(sum, 32);
#pragma unroll
    for (int c = 0; c < 32; ++c) {
        facc[c] += __shfl_xor(facc[c], 16);
        facc[c] += __shfl_xor(facc[c], 32);
    }

    if (part == 0) {
        float inv = 1.f / sum;
#pragma unroll
        for (int c4 = 0; c4 < 8; ++c4) {
            float4 o;
            o.x = facc[4 * c4] * inv; o.y = facc[4 * c4 + 1] * inv;
            o.z = facc[4 * c4 + 2] * inv; o.w = facc[4 * c4 + 3] * inv;
            *(float4*)&qptr[c4 * 4] = o;
        }
    }
}

__global__ __launch_bounds__(256) void proj_fb(
    const float* __restrict__ w, const float* __restrict__ bias, float* out)
{
    __shared__ ushort Apad[64 * 264];
    __shared__ ushort Bsm[256 * 40];
    const int t = threadIdx.x;
    const int m0 = blockIdx.x * 64;
    const int lane = t & 63, wv = t >> 6;
    const int qm = lane & 15, quad = lane >> 4;

    {
        int row = t >> 2, cb = (t & 3) * 64;
        const float4* src = (const float4*)&out[(size_t)(m0 + row) * 256 + cb];
#pragma unroll
        for (int i = 0; i < 16; ++i) {
            float4 v = src[i];
            ushort4 h;
            h.x = f2b(v.x); h.y = f2b(v.y); h.z = f2b(v.z); h.w = f2b(v.w);
            *(ushort4*)&Apad[row * 264 + cb + i * 4] = h;
        }
    }

    floatx4 acc[4][4];
#pragma unroll
    for (int i = 0; i < 4; ++i)
#pragma unroll
        for (int j = 0; j < 4; ++j) acc[i][j] = (floatx4){0.f, 0.f, 0.f, 0.f};

    __syncthreads();

    for (int k0 = 0; k0 < 256; k0 += 32) {
#pragma unroll
        for (int i = 0; i < 32; ++i) {
            int e = t + 256 * i;
            int kk = e >> 8, nn = e & 255;
            Bsm[nn * 40 + kk] = f2b(w[(size_t)(k0 + kk) * 256 + nn]);
        }
        __syncthreads();
        short8 af[4];
#pragma unroll
        for (int mt = 0; mt < 4; ++mt)
            af[mt] = *(const short8*)&Apad[(mt * 16 + qm) * 264 + k0 + quad * 8];
#pragma unroll
        for (int nt = 0; nt < 4; ++nt) {
            short8 bf = *(const short8*)&Bsm[(wv * 64 + nt * 16 + qm) * 40 + quad * 8];
#pragma unroll
            for (int mt = 0; mt < 4; ++mt)
                acc[mt][nt] = __builtin_amdgcn_mfma_f32_16x16x32_bf16(af[mt], bf, acc[mt][nt], 0, 0, 0);
        }
        __syncthreads();
    }

#pragma unroll
    for (int nt = 0; nt < 4; ++nt) {
        int c = wv * 64 + nt * 16 + qm;
        float bv = bias[c];
#pragma unroll
        for (int mt = 0; mt < 4; ++mt) {
#pragma unroll
            for (int r = 0; r < 4; ++r) {
                int m = m0 + mt * 16 + quad * 4 + r;
                out[(size_t)m * 256 + c] = acc[mt][nt][r] + bv;
            }
        }
    }
}

// ===========================================================================
extern "C" void kernel_launch(void* const* d_in, const int* in_sizes, int n_in,
                              void* d_out, int out_size, void* d_ws, size_t ws_size,
                              hipStream_t stream)
{
    const float* x     = (const float*)d_in[0];
    const float* wqkv  = (const float*)d_in[1];
    const float* wproj = (const float*)d_in[2];
    const float* bproj = (const float*)d_in[3];
    float* out = (float*)d_out;
    char* ws = (char*)d_ws;

    // fast-path ws layout (bytes):
    //   wqkvT   393,216 @ 0
    //   wprojT  131,072 @   393,216
    //   xb    3,211,264 @   524,288   (bf16)
    //   qb    3,211,264 @ 3,735,552   (f16, scale folded)
    //   kws   3,211,264 @ 6,946,816   (f16)
    //   vws   3,211,264 @ 10,158,080  (f16)
    //   ab    3,211,264 @ 13,369,344  (bf16) -> total 16,580,608
    if (ws_size >= 16580608ull) {
        ushort* wqkvT  = (ushort*)(ws);
        ushort* wprojT = (ushort*)(ws + 393216);
        ushort* xb     = (ushort*)(ws + 524288);
        ushort* qb     = (ushort*)(ws + 3735552);
        ushort* kws    = (ushort*)(ws + 6946816);
        ushort* vws    = (ushort*)(ws + 10158080);
        ushort* ab     = (ushort*)(ws + 13369344);

        hipLaunchKernelGGL(prep, dim3(162), dim3(256), 0, stream,
                           x, wqkv, wproj, xb, wqkvT, wprojT);
        hipLaunchKernelGGL(qkv_fast, dim3(6, 49), dim3(256), 0, stream,
                           xb, wqkvT, qb, kws, vws);
        hipLaunchKernelGGL(nattn, dim3(49, BATCH * HEADS), dim3(256), 0, stream,
                           kws, vws, qb, ab);
        hipLaunchKernelGGL(proj_fast, dim3(4, 98), dim3(256), 0, stream,
                           ab, wprojT, bproj, out);
    } else {
        ushort* kws = (ushort*)ws;
        ushort* vws = (ushort*)(ws + 3211264);
        hipLaunchKernelGGL(qkv_fb, dim3(12, 98), dim3(256), 0, stream,
                           x, wqkv, out, kws, vws);
        hipLaunchKernelGGL(nattn_fb, dim3(49, BATCH * HEADS), dim3(256), 0, stream,
                           kws, vws, out);
        hipLaunchKernelGGL(proj_fb, dim3(98), dim3(256), 0, stream,
                           wproj, bproj, out);
    }
}

// Round 14
// 110.380 us; speedup vs baseline: 1.3048x; 1.0094x over previous
//
#include <hip/hip_runtime.h>
#include <hip/hip_bf16.h>

#define HH 56
#define WW 56
#define NPOS 3136
#define BATCH 2
#define HEADS 8

typedef __attribute__((ext_vector_type(4))) float floatx4;
typedef __attribute__((ext_vector_type(8))) short short8;
typedef __attribute__((ext_vector_type(2))) _Float16 half2v;

static __device__ __forceinline__ ushort f2b(float f) {
    __hip_bfloat16 h = __float2bfloat16(f);
    return *reinterpret_cast<ushort*>(&h);
}
static __device__ __forceinline__ float b2f(ushort u) {
    return __uint_as_float(((uint)u) << 16);
}
static __device__ __forceinline__ ushort f2h(float f) {
    union { _Float16 h; ushort u; } c; c.h = (_Float16)f; return c.u;
}
static __device__ __forceinline__ half2v u2h2(uint u) {
    union { uint u; half2v h; } c; c.u = u; return c.h;
}

// async global->LDS, 16B per lane. LDS dest = wave-uniform base + lane*16.
static __device__ __forceinline__ void async16(const ushort* g, ushort* l) {
    __builtin_amdgcn_global_load_lds(
        (const __attribute__((address_space(1))) unsigned int*)g,
        (__attribute__((address_space(3))) unsigned int*)l, 16, 0, 0);
}

// fl32(10^(-j/4)) == np.float32 inv-freq table
__constant__ float INVF[16] = {
    1.0f,   0.5623413251903491f,   0.31622776601683794f,   0.17782794100389228f,
    0.1f,   0.05623413251903491f,  0.031622776601683794f,  0.017782794100389228f,
    0.01f,  0.005623413251903491f, 0.0031622776601683794f, 0.0017782794100389228f,
    0.001f, 0.0005623413251903491f,0.00031622776601683794f,0.00017782794100389228f
};

#define QSCALE 0.17677669529663687f   // 32^-0.5, folded into q at store

// ===========================================================================
// FAST PATH  (round-12 verified configuration: BK=32, 111.4 us, 4.88e-4)
// ===========================================================================

// Prepass: xb cvt (98) + wqkvT (48) + wprojT (16) = 162 blocks.
__global__ __launch_bounds__(256) void prep(
    const float* __restrict__ x,
    const float* __restrict__ wqkv, const float* __restrict__ wproj,
    ushort* __restrict__ xb, ushort* __restrict__ wqkvT,
    ushort* __restrict__ wprojT)
{
    __shared__ ushort Ls[64 * 65];
    const int bid = blockIdx.x, t = threadIdx.x;
    if (bid < 98) {                         // x fp32 -> bf16 (64 rows/block)
#pragma unroll
        for (int i = 0; i < 16; ++i) {
            int idx4 = bid * 4096 + i * 256 + t;      // float4 index
            float4 v = *(const float4*)&x[(size_t)idx4 * 4];
            ushort4 h; h.x = f2b(v.x); h.y = f2b(v.y); h.z = f2b(v.z); h.w = f2b(v.w);
            *(ushort4*)&xb[(size_t)idx4 * 4] = h;
        }
    } else if (bid < 146) {                 // wqkv (256,768) -> wqkvT (768,256)
        int l = bid - 98;
        int nb = (l % 12) * 64, kb = (l / 12) * 64;
#pragma unroll
        for (int i = 0; i < 16; ++i) {
            int e = t + 256 * i, kk = e >> 6, nn = e & 63;
            Ls[kk * 65 + nn] = f2b(wqkv[(size_t)(kb + kk) * 768 + nb + nn]);
        }
        __syncthreads();
#pragma unroll
        for (int i = 0; i < 16; ++i) {
            int e = t + 256 * i, nn = e >> 6, kk = e & 63;
            wqkvT[(size_t)(nb + nn) * 256 + kb + kk] = Ls[kk * 65 + nn];
        }
    } else {                                // wproj (256,256) -> wprojT
        int l = bid - 146;
        int nb = (l & 3) * 64, kb = (l >> 2) * 64;
#pragma unroll
        for (int i = 0; i < 16; ++i) {
            int e = t + 256 * i, kk = e >> 6, nn = e & 63;
            Ls[kk * 65 + nn] = f2b(wproj[(size_t)(kb + kk) * 256 + nb + nn]);
        }
        __syncthreads();
#pragma unroll
        for (int i = 0; i < 16; ++i) {
            int e = t + 256 * i, nn = e >> 6, kk = e & 63;
            wprojT[(size_t)(nb + nn) * 256 + kb + kk] = Ls[kk * 65 + nn];
        }
    }
}

// QKV GEMM 128x128 tile. A and B both via global_load_lds (bf16 sources).
// Inline __sincosf RoPE. q (scaled) / k / v stored F16 -> ws. grid (6, 49).
__global__ __launch_bounds__(256) void qkv_fast(
    const ushort* __restrict__ xb, const ushort* __restrict__ wqkvT,
    ushort* __restrict__ qb, ushort* __restrict__ kws, ushort* __restrict__ vws)
{
    __shared__ ushort Ab[128 * 32];
    __shared__ ushort Bb[128 * 32];
    const int t = threadIdx.x;
    const int lane = t & 63, wv = t >> 6;
    const int qm = lane & 15, quad = lane >> 4;
    const int m0 = blockIdx.y * 128, n0 = blockIdx.x * 128;
    const int wr = wv >> 1, wc = wv & 1;
    const int srow = lane >> 2, scol = (lane & 3) * 8;

    floatx4 acc[4][4];
#pragma unroll
    for (int i = 0; i < 4; ++i)
#pragma unroll
        for (int j = 0; j < 4; ++j) acc[i][j] = (floatx4){0.f, 0.f, 0.f, 0.f};

    for (int k0 = 0; k0 < 256; k0 += 32) {
#pragma unroll
        for (int j = 0; j < 2; ++j) {
            int rbase = wv * 32 + j * 16;
            async16(&xb[(size_t)(m0 + rbase + srow) * 256 + k0 + scol], &Ab[rbase * 32]);
            async16(&wqkvT[(size_t)(n0 + rbase + srow) * 256 + k0 + scol], &Bb[rbase * 32]);
        }
        __syncthreads();
        short8 af[4], bf[4];
#pragma unroll
        for (int mt = 0; mt < 4; ++mt)
            af[mt] = *(const short8*)&Ab[(wr * 64 + mt * 16 + qm) * 32 + quad * 8];
#pragma unroll
        for (int nt = 0; nt < 4; ++nt)
            bf[nt] = *(const short8*)&Bb[(wc * 64 + nt * 16 + qm) * 32 + quad * 8];
#pragma unroll
        for (int mt = 0; mt < 4; ++mt)
#pragma unroll
            for (int nt = 0; nt < 4; ++nt)
                acc[mt][nt] = __builtin_amdgcn_mfma_f32_16x16x32_bf16(af[mt], bf[nt], acc[mt][nt], 0, 0, 0);
        __syncthreads();
    }

    const int whichB = n0 >> 8;   // bx 0,1 -> q; 2,3 -> k; 4,5 -> v
#pragma unroll
    for (int mt = 0; mt < 4; ++mt) {
#pragma unroll
        for (int r = 0; r < 4; ++r) {
            int m = m0 + wr * 64 + mt * 16 + quad * 4 + r;
            int b = (m >= NPOS) ? 1 : 0;
            int pos = m - b * NPOS;
            float c0 = 0.f, s0 = 0.f, c1 = 0.f, s1 = 0.f;
            if (whichB < 2) {
                float posf = (float)pos;
                __sincosf(posf * INVF[qm >> 1], &s0, &c0);
                __sincosf(posf * INVF[8 + (qm >> 1)], &s1, &c1);
            }
#pragma unroll
            for (int nt = 0; nt < 4; ++nt) {
                int c = n0 + wc * 64 + nt * 16 + qm;
                int head = (c >> 5) & 7;
                int d = (nt & 1) * 16 + qm;
                float val = acc[mt][nt][r];
                if (whichB < 2) {
                    float other = __shfl_xor(val, 1);   // d parity == lane parity
                    float cf = (nt & 1) ? c1 : c0, sf = (nt & 1) ? s1 : s0;
                    val = (lane & 1) ? (val * cf + other * sf)
                                     : (val * cf - other * sf);
                }
                if (whichB == 0) {
                    qb[(size_t)m * 256 + head * 32 + d] = f2h(val * QSCALE);
                } else {
                    ushort* dst = (whichB == 1) ? kws : vws;
                    dst[(size_t)(((b << 3) + head) * NPOS + pos) * 32 + d] = f2h(val);
                }
            }
        }
    }
}

// Neighborhood attention: f16 q/k/v, single-pass softmax, v_dot2 scores,
// packed v_pk_fma_f16 V-accumulate. Output bf16 -> ab.
__global__ __launch_bounds__(256) void nattn(
    const ushort* __restrict__ kws, const ushort* __restrict__ vws,
    const ushort* __restrict__ qb, ushort* __restrict__ ab)
{
    __shared__ ushort Ksm[196 * 32];
    __shared__ ushort Vsm[196 * 32];
    const int t = threadIdx.x;
    const int bh = blockIdx.y;
    const int b = bh >> 3, head = bh & 7;
    const int ti = blockIdx.x / 7, tj = blockIdx.x % 7;
    const int ty0 = ti * 8, tx0 = tj * 8;
    const int r0 = min(max(ty0 - 3, 0), HH - 14);
    const int c0 = min(max(tx0 - 3, 0), WW - 14);
    const ushort* kbase = kws + (size_t)bh * NPOS * 32;
    const ushort* vbase = vws + (size_t)bh * NPOS * 32;

    for (int idx = t; idx < 196 * 4; idx += 256) {
        int p = idx >> 2, ch = idx & 3;
        int g = ((r0 + p / 14) * WW + (c0 + p % 14)) * 32 + ch * 8;
        *(uint4*)&Ksm[p * 32 + ch * 8] = *(const uint4*)&kbase[g];
        *(uint4*)&Vsm[p * 32 + ch * 8] = *(const uint4*)&vbase[g];
    }
    __syncthreads();

    const int lane = t & 63, wv = t >> 6;
    const int qsub = lane & 15, part = lane >> 4;
    const int qi = wv * 16 + qsub;
    const int qy = ty0 + (qi >> 3), qx = tx0 + (qi & 7);
    const int pos = qy * WW + qx;
    const size_t qoff = (size_t)(b * NPOS + pos) * 256 + head * 32;

    half2v qp[16];
    {
        const uint* q4 = (const uint*)(qb + qoff);
#pragma unroll
        for (int c2 = 0; c2 < 16; ++c2) qp[c2] = u2h2(q4[c2]);
    }

    const int rs = min(max(qy - 3, 0), HH - 7) - r0;
    const int cs = min(max(qx - 3, 0), WW - 7) - c0;

    float sum = 0.f;
    half2v vacc[16];
#pragma unroll
    for (int c = 0; c < 16; ++c) vacc[c] = (half2v){(_Float16)0.f, (_Float16)0.f};

#pragma unroll
    for (int j = 0; j < 13; ++j) {
        int kk = part + 4 * j;
        if (kk < 49) {
            int kp = (rs + kk / 7) * 14 + (cs + kk % 7);
            const uint4* Kp = (const uint4*)&Ksm[kp * 32];
            float s = 0.f;
#pragma unroll
            for (int c8 = 0; c8 < 4; ++c8) {
                uint4 u = Kp[c8];
#if __has_builtin(__builtin_amdgcn_fdot2)
                s = __builtin_amdgcn_fdot2(u2h2(u.x), qp[4 * c8 + 0], s, false);
                s = __builtin_amdgcn_fdot2(u2h2(u.y), qp[4 * c8 + 1], s, false);
                s = __builtin_amdgcn_fdot2(u2h2(u.z), qp[4 * c8 + 2], s, false);
                s = __builtin_amdgcn_fdot2(u2h2(u.w), qp[4 * c8 + 3], s, false);
#else
                half2v k0h = u2h2(u.x), k1h = u2h2(u.y), k2h = u2h2(u.z), k3h = u2h2(u.w);
                half2v q0 = qp[4 * c8 + 0], q1 = qp[4 * c8 + 1];
                half2v q2 = qp[4 * c8 + 2], q3 = qp[4 * c8 + 3];
                s += (float)k0h[0] * (float)q0[0] + (float)k0h[1] * (float)q0[1];
                s += (float)k1h[0] * (float)q1[0] + (float)k1h[1] * (float)q1[1];
                s += (float)k2h[0] * (float)q2[0] + (float)k2h[1] * (float)q2[1];
                s += (float)k3h[0] * (float)q3[0] + (float)k3h[1] * (float)q3[1];
#endif
            }
            float e = __expf(s);           // scale folded into q; |s| small
            sum += e;
            _Float16 eh = (_Float16)e;
            half2v e2 = (half2v){eh, eh};
            const uint4* Vp = (const uint4*)&Vsm[kp * 32];
#pragma unroll
            for (int c8 = 0; c8 < 4; ++c8) {
                uint4 u = Vp[c8];
                vacc[4 * c8 + 0] += e2 * u2h2(u.x);
                vacc[4 * c8 + 1] += e2 * u2h2(u.y);
                vacc[4 * c8 + 2] += e2 * u2h2(u.z);
                vacc[4 * c8 + 3] += e2 * u2h2(u.w);
            }
        }
    }
    sum += __shfl_xor(sum, 16);
    sum += __shfl_xor(sum, 32);

    float facc[32];
#pragma unroll
    for (int c2 = 0; c2 < 16; ++c2) {
        facc[2 * c2]     = (float)vacc[c2][0];
        facc[2 * c2 + 1] = (float)vacc[c2][1];
    }
#pragma unroll
    for (int c = 0; c < 32; ++c) {
        facc[c] += __shfl_xor(facc[c], 16);
        facc[c] += __shfl_xor(facc[c], 32);
    }

    if (part == 0) {
        float inv = 1.f / sum;
        uint* op = (uint*)(ab + qoff);
#pragma unroll
        for (int c2 = 0; c2 < 16; ++c2) {
            uint lo = f2b(facc[2 * c2] * inv);
            uint hi = f2b(facc[2 * c2 + 1] * inv);
            op[c2] = lo | (hi << 16);
        }
    }
}

// Projection 64x64 tiles; A (attn bf16) and B (wprojT) via async16. fp32 out.
__global__ __launch_bounds__(256) void proj_fast(
    const ushort* __restrict__ ab, const ushort* __restrict__ wprojT,
    const float* __restrict__ bias, float* __restrict__ out)
{
    __shared__ ushort Ap[64 * 32];
    __shared__ ushort Bp[64 * 32];
    const int t = threadIdx.x;
    const int lane = t & 63, wv = t >> 6;
    const int qm = lane & 15, quad = lane >> 4;
    const int n0 = blockIdx.x * 64, m0 = blockIdx.y * 64;
    const int wr = wv >> 1, wc = wv & 1;
    const int srow = lane >> 2, scol = (lane & 3) * 8;

    floatx4 acc[2][2];
#pragma unroll
    for (int i = 0; i < 2; ++i)
#pragma unroll
        for (int j = 0; j < 2; ++j) acc[i][j] = (floatx4){0.f, 0.f, 0.f, 0.f};

    for (int k0 = 0; k0 < 256; k0 += 32) {
        int rbase = wv * 16;
        async16(&ab[(size_t)(m0 + rbase + srow) * 256 + k0 + scol], &Ap[rbase * 32]);
        async16(&wprojT[(size_t)(n0 + rbase + srow) * 256 + k0 + scol], &Bp[rbase * 32]);
        __syncthreads();
        short8 af[2], bf[2];
#pragma unroll
        for (int mt = 0; mt < 2; ++mt)
            af[mt] = *(const short8*)&Ap[(wr * 32 + mt * 16 + qm) * 32 + quad * 8];
#pragma unroll
        for (int nt = 0; nt < 2; ++nt)
            bf[nt] = *(const short8*)&Bp[(wc * 32 + nt * 16 + qm) * 32 + quad * 8];
#pragma unroll
        for (int mt = 0; mt < 2; ++mt)
#pragma unroll
            for (int nt = 0; nt < 2; ++nt)
                acc[mt][nt] = __builtin_amdgcn_mfma_f32_16x16x32_bf16(af[mt], bf[nt], acc[mt][nt], 0, 0, 0);
        __syncthreads();
    }

#pragma unroll
    for (int nt = 0; nt < 2; ++nt) {
        int c = n0 + wc * 32 + nt * 16 + qm;
        float bv = bias[c];
#pragma unroll
        for (int mt = 0; mt < 2; ++mt) {
#pragma unroll
            for (int r = 0; r < 4; ++r) {
                int m = m0 + wr * 32 + mt * 16 + quad * 4 + r;
                out[(size_t)m * 256 + c] = acc[mt][nt][r] + bv;
            }
        }
    }
}

// ===========================================================================
// FALLBACK PATH (r8 kernels, verified; used only if ws too small)
// ===========================================================================
__global__ __launch_bounds__(256) void qkv_fb(
    const float* __restrict__ x, const float* __restrict__ w,
    float* __restrict__ qa, ushort* __restrict__ kws, ushort* __restrict__ vws)
{
    __shared__ ushort Asm[64 * 40];
    __shared__ ushort Bsm[64 * 40];
    const int t = threadIdx.x;
    const int m0 = blockIdx.y * 64;
    const int n0 = blockIdx.x * 64;
    const int lane = t & 63, wv = t >> 6;
    const int qm = lane & 15, quad = lane >> 4;

    floatx4 acc[4];
#pragma unroll
    for (int i = 0; i < 4; ++i) acc[i] = (floatx4){0.f, 0.f, 0.f, 0.f};

    for (int k0 = 0; k0 < 256; k0 += 32) {
#pragma unroll
        for (int i = 0; i < 2; ++i) {
            int p = t + 256 * i;
            int row = p >> 3, f4 = p & 7;
            float4 v = *(const float4*)&x[(size_t)(m0 + row) * 256 + k0 + f4 * 4];
            ushort4 h;
            h.x = f2b(v.x); h.y = f2b(v.y); h.z = f2b(v.z); h.w = f2b(v.w);
            *(ushort4*)&Asm[row * 40 + f4 * 4] = h;
        }
#pragma unroll
        for (int i = 0; i < 8; ++i) {
            int e = t + 256 * i;
            int kk = e >> 6, nn = e & 63;
            Bsm[nn * 40 + kk] = f2b(w[(size_t)(k0 + kk) * 768 + n0 + nn]);
        }
        __syncthreads();
        short8 af = *(const short8*)&Asm[(wv * 16 + qm) * 40 + quad * 8];
#pragma unroll
        for (int nt = 0; nt < 4; ++nt) {
            short8 bf = *(const short8*)&Bsm[(nt * 16 + qm) * 40 + quad * 8];
            acc[nt] = __builtin_amdgcn_mfma_f32_16x16x32_bf16(af, bf, acc[nt], 0, 0, 0);
        }
        __syncthreads();
    }

    const int whichB = n0 >> 8;
#pragma unroll
    for (int r = 0; r < 4; ++r) {
        int m = m0 + wv * 16 + quad * 4 + r;
        int b = (m >= NPOS) ? 1 : 0;
        int pos = m - b * NPOS;
        float cf[2], sf[2];
        if (whichB < 2) {
            float posf = (float)pos;
            __sincosf(posf * INVF[qm >> 1], &sf[0], &cf[0]);
            __sincosf(posf * INVF[8 + (qm >> 1)], &sf[1], &cf[1]);
        }
#pragma unroll
        for (int nt = 0; nt < 4; ++nt) {
            int par = nt & 1;
            int d = par * 16 + qm;
            int head = ((n0 >> 5) & 7) + (nt >> 1);
            float val = acc[nt][r];
            if (whichB < 2) {
                float other = __shfl_xor(val, 1);
                val = (lane & 1) ? (val * cf[par] + other * sf[par])
                                 : (val * cf[par] - other * sf[par]);
            }
            if (whichB == 0) {
                qa[(size_t)m * 256 + head * 32 + d] = val;
            } else {
                ushort* dst = (whichB == 1) ? kws : vws;
                dst[(size_t)(((b << 3) + head) * NPOS + pos) * 32 + d] = f2b(val);
            }
        }
    }
}

__global__ __launch_bounds__(256) void nattn_fb(
    const ushort* __restrict__ kws, const ushort* __restrict__ vws, float* qa)
{
    __shared__ ushort Ksm[196 * 32];
    __shared__ ushort Vsm[196 * 32];
    const int t = threadIdx.x;
    const int bh = blockIdx.y;
    const int b = bh >> 3, head = bh & 7;
    const int ti = blockIdx.x / 7, tj = blockIdx.x % 7;
    const int ty0 = ti * 8, tx0 = tj * 8;
    const int r0 = min(max(ty0 - 3, 0), HH - 14);
    const int c0 = min(max(tx0 - 3, 0), WW - 14);
    const ushort* kbase = kws + (size_t)bh * NPOS * 32;
    const ushort* vbase = vws + (size_t)bh * NPOS * 32;

    for (int idx = t; idx < 196 * 4; idx += 256) {
        int p = idx >> 2, ch = idx & 3;
        int g = ((r0 + p / 14) * WW + (c0 + p % 14)) * 32 + ch * 8;
        *(uint4*)&Ksm[p * 32 + ch * 8] = *(const uint4*)&kbase[g];
        *(uint4*)&Vsm[p * 32 + ch * 8] = *(const uint4*)&vbase[g];
    }
    __syncthreads();

    const int lane = t & 63, wv = t >> 6;
    const int qsub = lane & 15, part = lane >> 4;
    const int qi = wv * 16 + qsub;
    const int qy = ty0 + (qi >> 3), qx = tx0 + (qi & 7);
    const int pos = qy * WW + qx;
    float* qptr = qa + (size_t)(b * NPOS + pos) * 256 + head * 32;

    float qf[32];
#pragma unroll
    for (int c4 = 0; c4 < 8; ++c4) {
        float4 v = *(const float4*)&qptr[c4 * 4];
        qf[4 * c4] = v.x; qf[4 * c4 + 1] = v.y; qf[4 * c4 + 2] = v.z; qf[4 * c4 + 3] = v.w;
    }

    const int rs = min(max(qy - 3, 0), HH - 7) - r0;
    const int cs = min(max(qx - 3, 0), WW - 7) - c0;

    float sum = 0.f;
    float facc[32];
#pragma unroll
    for (int c = 0; c < 32; ++c) facc[c] = 0.f;
#pragma unroll
    for (int j = 0; j < 13; ++j) {
        int kk = part + 4 * j;
        if (kk < 49) {
            int kp = (rs + kk / 7) * 14 + (cs + kk % 7);
            const uint4* Kp = (const uint4*)&Ksm[kp * 32];
            float s = 0.f;
#pragma unroll
            for (int c8 = 0; c8 < 4; ++c8) {
                uint4 u = Kp[c8];
                const float* qv = qf + 8 * c8;
                s += qv[0] * b2f((ushort)u.x) + qv[1] * b2f((ushort)(u.x >> 16));
                s += qv[2] * b2f((ushort)u.y) + qv[3] * b2f((ushort)(u.y >> 16));
                s += qv[4] * b2f((ushort)u.z) + qv[5] * b2f((ushort)(u.z >> 16));
                s += qv[6] * b2f((ushort)u.w) + qv[7] * b2f((ushort)(u.w >> 16));
            }
            float e = __expf(s * 0.17677669529663687f);
            sum += e;
            const uint4* Vp = (const uint4*)&Vsm[kp * 32];
#pragma unroll
            for (int c8 = 0; c8 < 4; ++c8) {
                uint4 u = Vp[c8];
                float* fv = facc + 8 * c8;
                fv[0] += e * b2f((ushort)u.x); fv[1] += e * b2f((ushort)(u.x >> 16));
                fv[2] += e * b2f((ushort)u.y); fv[3] += e * b2f((ushort)(u.y >> 16));
                fv[4] += e * b2f((ushort)u.z); fv[5] += e * b2f((ushort)(u.z >> 16));
                fv[6] += e * b2f((ushort)u.w); fv[7] += e * b2f((ushort)(u.w >> 16));
            }
        }
    }
    sum += __shfl_xor(sum, 16);
    sum += __shfl_xor(sum, 32);
#pragma unroll
    for (int c = 0; c < 32; ++c) {
        facc[c] += __shfl_xor(facc[c], 16);
        facc[c] += __shfl_xor(facc[c], 32);
    }

    if (part == 0) {
        float inv = 1.f / sum;
#pragma unroll
        for (int c4 = 0; c4 < 8; ++c4) {
            float4 o;
            o.x = facc[4 * c4] * inv; o.y = facc[4 * c4 + 1] * inv;
            o.z = facc[4 * c4 + 2] * inv; o.w = facc[4 * c4 + 3] * inv;
            *(float4*)&qptr[c4 * 4] = o;
        }
    }
}

__global__ __launch_bounds__(256) void proj_fb(
    const float* __restrict__ w, const float* __restrict__ bias, float* out)
{
    __shared__ ushort Apad[64 * 264];
    __shared__ ushort Bsm[256 * 40];
    const int t = threadIdx.x;
    const int m0 = blockIdx.x * 64;
    const int lane = t & 63, wv = t >> 6;
    const int qm = lane & 15, quad = lane >> 4;

    {
        int row = t >> 2, cb = (t & 3) * 64;
        const float4* src = (const float4*)&out[(size_t)(m0 + row) * 256 + cb];
#pragma unroll
        for (int i = 0; i < 16; ++i) {
            float4 v = src[i];
            ushort4 h;
            h.x = f2b(v.x); h.y = f2b(v.y); h.z = f2b(v.z); h.w = f2b(v.w);
            *(ushort4*)&Apad[row * 264 + cb + i * 4] = h;
        }
    }

    floatx4 acc[4][4];
#pragma unroll
    for (int i = 0; i < 4; ++i)
#pragma unroll
        for (int j = 0; j < 4; ++j) acc[i][j] = (floatx4){0.f, 0.f, 0.f, 0.f};

    __syncthreads();

    for (int k0 = 0; k0 < 256; k0 += 32) {
#pragma unroll
        for (int i = 0; i < 32; ++i) {
            int e = t + 256 * i;
            int kk = e >> 8, nn = e & 255;
            Bsm[nn * 40 + kk] = f2b(w[(size_t)(k0 + kk) * 256 + nn]);
        }
        __syncthreads();
        short8 af[4];
#pragma unroll
        for (int mt = 0; mt < 4; ++mt)
            af[mt] = *(const short8*)&Apad[(mt * 16 + qm) * 264 + k0 + quad * 8];
#pragma unroll
        for (int nt = 0; nt < 4; ++nt) {
            short8 bf = *(const short8*)&Bsm[(wv * 64 + nt * 16 + qm) * 40 + quad * 8];
#pragma unroll
            for (int mt = 0; mt < 4; ++mt)
                acc[mt][nt] = __builtin_amdgcn_mfma_f32_16x16x32_bf16(af[mt], bf, acc[mt][nt], 0, 0, 0);
        }
        __syncthreads();
    }

#pragma unroll
    for (int nt = 0; nt < 4; ++nt) {
        int c = wv * 64 + nt * 16 + qm;
        float bv = bias[c];
#pragma unroll
        for (int mt = 0; mt < 4; ++mt) {
#pragma unroll
            for (int r = 0; r < 4; ++r) {
                int m = m0 + mt * 16 + quad * 4 + r;
                out[(size_t)m * 256 + c] = acc[mt][nt][r] + bv;
            }
        }
    }
}

// ===========================================================================
extern "C" void kernel_launch(void* const* d_in, const int* in_sizes, int n_in,
                              void* d_out, int out_size, void* d_ws, size_t ws_size,
                              hipStream_t stream)
{
    const float* x     = (const float*)d_in[0];
    const float* wqkv  = (const float*)d_in[1];
    const float* wproj = (const float*)d_in[2];
    const float* bproj = (const float*)d_in[3];
    float* out = (float*)d_out;
    char* ws = (char*)d_ws;

    // fast-path ws layout (bytes):
    //   wqkvT   393,216 @ 0
    //   wprojT  131,072 @   393,216
    //   xb    3,211,264 @   524,288   (bf16)
    //   qb    3,211,264 @ 3,735,552   (f16, scale folded)
    //   kws   3,211,264 @ 6,946,816   (f16)
    //   vws   3,211,264 @ 10,158,080  (f16)
    //   ab    3,211,264 @ 13,369,344  (bf16) -> total 16,580,608
    if (ws_size >= 16580608ull) {
        ushort* wqkvT  = (ushort*)(ws);
        ushort* wprojT = (ushort*)(ws + 393216);
        ushort* xb     = (ushort*)(ws + 524288);
        ushort* qb     = (ushort*)(ws + 3735552);
        ushort* kws    = (ushort*)(ws + 6946816);
        ushort* vws    = (ushort*)(ws + 10158080);
        ushort* ab     = (ushort*)(ws + 13369344);

        hipLaunchKernelGGL(prep, dim3(162), dim3(256), 0, stream,
                           x, wqkv, wproj, xb, wqkvT, wprojT);
        hipLaunchKernelGGL(qkv_fast, dim3(6, 49), dim3(256), 0, stream,
                           xb, wqkvT, qb, kws, vws);
        hipLaunchKernelGGL(nattn, dim3(49, BATCH * HEADS), dim3(256), 0, stream,
                           kws, vws, qb, ab);
        hipLaunchKernelGGL(proj_fast, dim3(4, 98), dim3(256), 0, stream,
                           ab, wprojT, bproj, out);
    } else {
        ushort* kws = (ushort*)ws;
        ushort* vws = (ushort*)(ws + 3211264);
        hipLaunchKernelGGL(qkv_fb, dim3(12, 98), dim3(256), 0, stream,
                           x, wqkv, out, kws, vws);
        hipLaunchKernelGGL(nattn_fb, dim3(49, BATCH * HEADS), dim3(256), 0, stream,
                           kws, vws, out);
        hipLaunchKernelGGL(proj_fb, dim3(98), dim3(256), 0, stream,
                           wproj, bproj, out);
    }
}